// Round 3
// baseline (263.086 us; speedup 1.0000x reference)
//
#include <hip/hip_runtime.h>
#include <hip/hip_bf16.h>
#include <math.h>

typedef unsigned short ushort_t;
typedef unsigned char uchar_t;
typedef unsigned int uint_t;
typedef __attribute__((ext_vector_type(8))) short bf16x8;   // 8 bf16 = 4 VGPRs
typedef __attribute__((ext_vector_type(4))) float f32x4;
typedef __attribute__((ext_vector_type(2))) long longx2;    // 16 B = ksub0/ksub1 fp8 frags

#define AS1 __attribute__((address_space(1)))
#define AS3 __attribute__((address_space(3)))

__device__ __forceinline__ void gld_lds16(const void* g, void* l) {
  // async global->LDS, 16B per lane; LDS dest = wave-uniform base + lane*16
  __builtin_amdgcn_global_load_lds((const AS1 void*)g, (AS3 void*)l, 16, 0, 0);
}

__device__ __forceinline__ ushort_t f32_to_bf16_bits(float v) {
  __hip_bfloat16 b = __float2bfloat16(v);
  return *(ushort_t*)&b;
}

__device__ __forceinline__ uint_t pack_fp8x4(float4 v, float sc) {
  int r = __builtin_amdgcn_cvt_pk_fp8_f32(v.x * sc, v.y * sc, 0, false);
  r = __builtin_amdgcn_cvt_pk_fp8_f32(v.z * sc, v.w * sc, r, true);
  return (uint_t)r;
}

// ================= tiled operand layout =================
// Unit tile = 16 rows x 64 B, stored contiguously (1024 B). Tile index =
// rowblock * nKtiles + kt. Within a tile row rl, the 64 B is split into 16-B
// units XOR-permuted by a per-row key so MFMA fragment ds_read_b128 are
// conflict-free:
//   bf16: unit u = k[16u..16u+16);      phys = u ^ ((rl>>1)&3)
//   fp8 : unit u = {ksub0 k[8u..8u+8) | ksub1 k[32+8u..+8)};  phys = u ^ ((rl>>1)&3)
// global_load_lds copies tiles verbatim, so the LDS image equals the global image.

// ---------------- single prep kernel ----------------
__global__ __launch_bounds__(256) void prep(const float4* __restrict__ h,
                                            uchar_t* __restrict__ h8, int rowsH,
                                            const float4* __restrict__ p,
                                            uchar_t* __restrict__ p8, int rowsP,
                                            const float* __restrict__ pc,
                                            ushort_t* __restrict__ pcT,
                                            int P, int C, int normBlocks) {
  __shared__ float tile[32][33];
  if ((int)blockIdx.x < normBlocks) {
    int r = (blockIdx.x * 256 + threadIdx.x) >> 6;
    const int lane = threadIdx.x & 63;
    const float4* xr;
    uchar_t* o8;
    if (r < rowsH) {
      xr = h + (size_t)r * 192;          // 768 floats = 192 float4
      o8 = h8;
    } else {
      r -= rowsH;
      if (r >= rowsP) return;
      xr = p + (size_t)r * 192;
      o8 = p8;
    }
    float4 v0 = xr[lane];
    float4 v1 = xr[lane + 64];
    float4 v2 = xr[lane + 128];
    float ss = v0.x * v0.x + v0.y * v0.y + v0.z * v0.z + v0.w * v0.w
             + v1.x * v1.x + v1.y * v1.y + v1.z * v1.z + v1.w * v1.w
             + v2.x * v2.x + v2.y * v2.y + v2.z * v2.z + v2.w * v2.w;
#pragma unroll
    for (int off = 32; off > 0; off >>= 1) ss += __shfl_xor(ss, off, 64);
    const float sc = 4.0f / fmaxf(sqrtf(ss), 1e-12f);
    // lane L holds k-local = 4*(L&15)+{0..3} of tile ktb = L>>4 in each 256-group.
    // fp8 paired-unit layout: u=(L&7)>>1, ksub=(L&15)>>3, inner=4*(L&1)
    const int rb = r >> 4, rl = r & 15;
    const int key4 = (rl >> 1) & 3;
    const int u = (lane & 7) >> 1;
    const int ksub = (lane & 15) >> 3;
    const int cphys = ((u ^ key4) << 4) + (ksub << 3) + ((lane & 1) << 2);
    const int ktb = lane >> 4;                        // tile within group
    uchar_t* rowbase = o8 + (size_t)rb * 12 * 1024 + rl * 64 + cphys;
    *(uint_t*)(rowbase + (size_t)(ktb) * 1024)     = pack_fp8x4(v0, sc);
    *(uint_t*)(rowbase + (size_t)(4 + ktb) * 1024) = pack_fp8x4(v1, sc);
    *(uint_t*)(rowbase + (size_t)(8 + ktb) * 1024) = pack_fp8x4(v2, sc);
  } else {
    const int b = blockIdx.x - normBlocks;
    const int nkb = P / 32;                   // k-tiles per pcT row-block (=64)
    const int bk = b % nkb, bc = b / nkb;
    const int k0 = bk * 32, c0 = bc * 32;
    const int tx = threadIdx.x & 31, ty = threadIdx.x >> 5;   // ty 0..7
#pragma unroll
    for (int rr = 0; rr < 4; ++rr) {
      const int c = c0 + tx;
      tile[ty + rr * 8][tx] = (c < C) ? pc[(size_t)(k0 + ty + rr * 8) * C + c] : 0.f;
    }
    __syncthreads();
    const int c2 = tx >> 3, off = tx & 7;
#pragma unroll
    for (int rr = 0; rr < 4; ++rr) {
      const int row = c0 + ty + rr * 8;       // pcT row (class dim)
      const int rb = row >> 4, rl = row & 15;
      const int key4 = (rl >> 1) & 3;
      size_t us = (((size_t)rb * nkb + bk) * 16 + rl) * 32 + ((c2 ^ key4) << 3) + off;
      pcT[us] = f32_to_bf16_bits(tile[tx][ty + rr * 8]);
    }
  }
}

// ======== schedule primitives ========
#define BARRIER() do { asm volatile("" ::: "memory"); __builtin_amdgcn_s_barrier(); \
                       asm volatile("" ::: "memory"); } while (0)
#define LGKM0()   asm volatile("s_waitcnt lgkmcnt(0)" ::: "memory")
#define VM8()     asm volatile("s_waitcnt vmcnt(8)" ::: "memory")
#define VM4()     asm volatile("s_waitcnt vmcnt(4)" ::: "memory")
#define VM2()     asm volatile("s_waitcnt vmcnt(2)" ::: "memory")
#define VM0()     asm volatile("s_waitcnt vmcnt(0)" ::: "memory")
#define PRIO1()   __builtin_amdgcn_s_setprio(1)
#define PRIO0()   __builtin_amdgcn_s_setprio(0)
#define SB0()     __builtin_amdgcn_sched_barrier(0)
#define MM(a, b, c)  __builtin_amdgcn_mfma_f32_16x16x32_bf16(a, b, c, 0, 0, 0)
#define MM8(a, b, c) __builtin_amdgcn_mfma_f32_16x16x32_fp8_fp8(a, b, c, 0, 0, 0)

// =================================================================================
// GEMM1: 256x256 fp8, 4-phase LOOKAHEAD pipeline.  act = epilogue(h8 @ p8^T).
// Phase p: {ds_read frags for phase p+1 | stage 1 quarter-tile | MFMA(frags of p) |
//           lgkm0 | barrier}.  Stage cadence: c0(T)@(T-2).ph1 .. c3(T)@(T-2).ph4.
// vmcnt(2) at ph3-front => tile kt+1 fully landed before its B/A01 lookahead reads.
// Region proof: every LDS region's readers drain (end-of-phase lgkm0+barrier)
// strictly before its overwriting stage issues; prologue preload gets its own
// lgkm0+barrier before ph1's first stage into the same region.
// =================================================================================
#define MFMA16_8(I0, I1, A0_, A1_)                                                              \
  acc[I0][0] = MM8(A0_[0], bC[0][0], acc[I0][0]); acc[I0][1] = MM8(A0_[0], bC[1][0], acc[I0][1]); \
  acc[I0][2] = MM8(A0_[0], bC[2][0], acc[I0][2]); acc[I0][3] = MM8(A0_[0], bC[3][0], acc[I0][3]); \
  acc[I1][0] = MM8(A1_[0], bC[0][0], acc[I1][0]); acc[I1][1] = MM8(A1_[0], bC[1][0], acc[I1][1]); \
  acc[I1][2] = MM8(A1_[0], bC[2][0], acc[I1][2]); acc[I1][3] = MM8(A1_[0], bC[3][0], acc[I1][3]); \
  acc[I0][0] = MM8(A0_[1], bC[0][1], acc[I0][0]); acc[I0][1] = MM8(A0_[1], bC[1][1], acc[I0][1]); \
  acc[I0][2] = MM8(A0_[1], bC[2][1], acc[I0][2]); acc[I0][3] = MM8(A0_[1], bC[3][1], acc[I0][3]); \
  acc[I1][0] = MM8(A1_[1], bC[0][1], acc[I1][0]); acc[I1][1] = MM8(A1_[1], bC[1][1], acc[I1][1]); \
  acc[I1][2] = MM8(A1_[1], bC[2][1], acc[I1][2]); acc[I1][3] = MM8(A1_[1], bC[3][1], acc[I1][3])

__launch_bounds__(512, 2)
__global__ void gemm1_fp8_la(const uchar_t* __restrict__ A, const uchar_t* __restrict__ B,
                             ushort_t* __restrict__ act, const float* __restrict__ tptr,
                             int nKt, int actKT, int gx, int gxlog2) {
  __shared__ __align__(16) uchar_t sm1[65536];
  const int tid = threadIdx.x, lane = tid & 63, wave = tid >> 6;   // 8 waves
  const int wm = wave >> 2, wn = wave & 3;                         // 2M x 4N
  const int lid = blockIdx.x, xcd = lid & 7, q = lid >> 3;
  const int tb = q & (gx - 1), sb = ((q >> gxlog2) << 3) | xcd;

  f32x4 acc[8][4];
#pragma unroll
  for (int i = 0; i < 8; ++i)
#pragma unroll
    for (int j = 0; j < 4; ++j) acc[i][j] = (f32x4){0.f, 0.f, 0.f, 0.f};

  // staging roles: wave w stages B tiles {w, w+8}; A tiles {m2, m3}
  const int m2 = (wave & 4) ? wave + 4 : wave;    // {0,1,2,3, 8,9,10,11}
  const int m3 = m2 + 4;                          // {4,5,6,7, 12,13,14,15}
  const uchar_t* Apl = A + (((size_t)(sb * 16) * nKt) << 10) + lane * 16;
  const uchar_t* Bpl = B + (((size_t)(tb * 16) * nKt) << 10) + lane * 16;

  const int fr = lane & 15, g = lane >> 4;
  const int rdoff = fr * 64 + ((g ^ ((fr >> 1) & 3)) << 4);
  const int wm8 = wm * 8, wn4 = wn * 4;

#define F_STA(m_, T_, bo_) gld_lds16(Apl + (((size_t)(m_) * nKt + (T_)) << 10), \
                                     sm1 + (bo_) + ((m_) << 10))
#define F_STB(m_, T_, bo_) gld_lds16(Bpl + (((size_t)(m_) * nKt + (T_)) << 10), \
                                     sm1 + (bo_) + 16384 + ((m_) << 10))
#define F_DSA_AT(bo_, i_) (*(const longx2*)(sm1 + (bo_) + ((wm8 + (i_)) << 10) + rdoff))
#define F_DSB_AT(bo_, j_) (*(const longx2*)(sm1 + (bo_) + 16384 + ((wn4 + (j_)) << 10) + rdoff))

  // prologue: stage tiles 0,1 in steady cadence order c0,c1,c2,c3
  F_STB(wave, 0, 0); F_STB(wave + 8, 0, 0); F_STA(m2, 0, 0); F_STA(m3, 0, 0);
  F_STB(wave, 1, 32768); F_STB(wave + 8, 1, 32768); F_STA(m2, 1, 32768); F_STA(m3, 1, 32768);
  VM4(); BARRIER();                       // tile 0 landed (tile 1's 4 in flight)

  longx2 bC[4], aP[2], bN[4], aN[2];
  bC[0] = F_DSB_AT(0, 0); bC[1] = F_DSB_AT(0, 1); bC[2] = F_DSB_AT(0, 2); bC[3] = F_DSB_AT(0, 3);
  aP[0] = F_DSA_AT(0, 0); aP[1] = F_DSA_AT(0, 1);
  LGKM0(); BARRIER();                     // preload drained before ph1's c0(2) overwrite

#pragma unroll 2
  for (int kt = 0; kt < nKt; ++kt) {
    const int bufoff = (kt & 1) << 15;
    const int nbo = ((kt + 1) & 1) << 15;
    longx2 aQ[2];
    // ---- ph1: MFMA rows 0,1; read rows 2,3; stage c0(kt+2) ----
    aQ[0] = F_DSA_AT(bufoff, 2); aQ[1] = F_DSA_AT(bufoff, 3);
    if (kt + 2 < nKt) F_STB(wave, kt + 2, bufoff);
    SB0(); PRIO1(); MFMA16_8(0, 1, aP[0], aP[1]); PRIO0(); LGKM0(); SB0(); BARRIER();
    // ---- ph2: MFMA rows 2,3; read rows 4,5; stage c1(kt+2) ----
    aP[0] = F_DSA_AT(bufoff, 4); aP[1] = F_DSA_AT(bufoff, 5);
    if (kt + 2 < nKt) F_STB(wave + 8, kt + 2, bufoff);
    SB0(); PRIO1(); MFMA16_8(2, 3, aQ[0], aQ[1]); PRIO0(); LGKM0(); SB0(); BARRIER();
    // ---- ph3: vmcnt; MFMA rows 4,5; read rows 6,7 + B[kt+1] half; stage c2(kt+2) ----
    if (kt + 1 < nKt) { if (kt + 2 < nKt) { VM2(); } else { VM0(); } }
    aQ[0] = F_DSA_AT(bufoff, 6); aQ[1] = F_DSA_AT(bufoff, 7);
    if (kt + 1 < nKt) { bN[0] = F_DSB_AT(nbo, 0); bN[1] = F_DSB_AT(nbo, 1); }
    if (kt + 2 < nKt) F_STA(m2, kt + 2, bufoff);
    SB0(); PRIO1(); MFMA16_8(4, 5, aP[0], aP[1]); PRIO0(); LGKM0(); SB0(); BARRIER();
    // ---- ph4: MFMA rows 6,7; read B[kt+1] rest + A01[kt+1]; stage c3(kt+2) ----
    if (kt + 1 < nKt) {
      bN[2] = F_DSB_AT(nbo, 2); bN[3] = F_DSB_AT(nbo, 3);
      aN[0] = F_DSA_AT(nbo, 0); aN[1] = F_DSA_AT(nbo, 1);
    }
    if (kt + 2 < nKt) F_STA(m3, kt + 2, bufoff);
    SB0(); PRIO1(); MFMA16_8(6, 7, aQ[0], aQ[1]); PRIO0(); LGKM0(); SB0(); BARRIER();
    bC[0] = bN[0]; bC[1] = bN[1]; bC[2] = bN[2]; bC[3] = bN[3];
    aP[0] = aN[0]; aP[1] = aN[1];
  }

  float tmp = *tptr;
  const float tau = log1pf(expf(tmp));
  // C/D layout: col = lane&15, row = (lane>>4)*4 + reg   [measured m89/m91]
  const int crow = g * 4;
  const int rowB = sb * 256 + wm * 128, colB = tb * 256 + wn * 64;
#pragma unroll
  for (int i = 0; i < 8; ++i)
#pragma unroll
    for (int j = 0; j < 4; ++j) {
      const int col = colB + j * 16 + fr;
      const size_t ktile = col >> 5;
      const int c2 = (col >> 3) & 3, co = col & 7;
#pragma unroll
      for (int rr = 0; rr < 4; ++rr) {
        const int row = rowB + i * 16 + crow + rr;
        const int rb = row >> 4, rl = row & 15;
        const int key4 = (rl >> 1) & 3;
        float d2 = fmaxf(2.0f - acc[i][j][rr] * 0.125f, 0.0f);   // acc = 16*dot
        float a = __expf(-tau * sqrtf(d2));
        act[(((size_t)rb * actKT + ktile) * 16 + rl) * 32 + ((c2 ^ key4) << 3) + co] =
            f32_to_bf16_bits(a);
      }
    }
}

// =================================================================================
// GEMM2: 256x256 bf16, 4-phase LOOKAHEAD pipeline.  out = act @ pcT^T.
// Same skeleton as gemm1_la; 2 gld_lds per wave per phase (half-tiles);
// vmcnt(4) at ph3-front => tile kt+1 fully landed before its lookahead reads.
// =================================================================================
#define MFMA16(I0, I1, AP, BC)                                                          \
  acc[I0][0] = MM(AP[0], BC[0], acc[I0][0]); acc[I0][1] = MM(AP[0], BC[2], acc[I0][1]); \
  acc[I0][2] = MM(AP[0], BC[4], acc[I0][2]); acc[I0][3] = MM(AP[0], BC[6], acc[I0][3]); \
  acc[I1][0] = MM(AP[2], BC[0], acc[I1][0]); acc[I1][1] = MM(AP[2], BC[2], acc[I1][1]); \
  acc[I1][2] = MM(AP[2], BC[4], acc[I1][2]); acc[I1][3] = MM(AP[2], BC[6], acc[I1][3]); \
  acc[I0][0] = MM(AP[1], BC[1], acc[I0][0]); acc[I0][1] = MM(AP[1], BC[3], acc[I0][1]); \
  acc[I0][2] = MM(AP[1], BC[5], acc[I0][2]); acc[I0][3] = MM(AP[1], BC[7], acc[I0][3]); \
  acc[I1][0] = MM(AP[3], BC[1], acc[I1][0]); acc[I1][1] = MM(AP[3], BC[3], acc[I1][1]); \
  acc[I1][2] = MM(AP[3], BC[5], acc[I1][2]); acc[I1][3] = MM(AP[3], BC[7], acc[I1][3])

__launch_bounds__(512, 2)
__global__ void gemm2_bf16_la(const ushort_t* __restrict__ A,
                              const ushort_t* __restrict__ B,
                              float* __restrict__ out, int ldc, int ncols,
                              int nKt) {
  __shared__ __align__(16) uchar_t sm[131072];
  const int tid = threadIdx.x, lane = tid & 63, wave = tid >> 6;   // 8 waves
  const int wm = wave >> 2, wn = wave & 3;                         // 2M x 4N
  const int lid = blockIdx.x, xcd = lid & 7, q = lid >> 3;
  const int tb = q & 3, sb = ((q >> 2) << 3) | xcd;   // col-tile 0..3, row-tile 0..63

  f32x4 acc[8][4];
#pragma unroll
  for (int i = 0; i < 8; ++i)
#pragma unroll
    for (int j = 0; j < 4; ++j) acc[i][j] = (f32x4){0.f, 0.f, 0.f, 0.f};

  const int lw = wave & 1, rw = wave >> 1;
  const uchar_t* Apl = (const uchar_t*)A + ((size_t)(sb * 16) << 16) + (lw << 10) + lane * 16;
  const uchar_t* Bpl = (const uchar_t*)B + ((size_t)(tb * 16) << 16) + (lw << 10) + lane * 16;

  const int fr = lane & 15, g = lane >> 4;
  const int rdoff = fr * 64 + ((g ^ ((fr >> 1) & 3)) << 4);
  const int wm8 = wm * 8, wn4 = wn * 4;

#define STA(r_, T_, bo_) gld_lds16(Apl + (((size_t)(r_) << 16) + ((size_t)(T_) << 11)), \
                                   sm + (bo_) + ((((r_) << 1) + lw) << 10))
#define STB(r_, T_, bo_) gld_lds16(Bpl + (((size_t)(r_) << 16) + ((size_t)(T_) << 11)), \
                                   sm + (bo_) + 32768 + ((((r_) << 1) + lw) << 10))
#define DSA_AT(bo_, i_, l_) (*(const bf16x8*)(sm + (bo_) + (((wm8 + (i_)) * 2 + (l_)) << 10) + rdoff))
#define DSB_AT(bo_, j_, l_) (*(const bf16x8*)(sm + (bo_) + 32768 + (((wn4 + (j_)) * 2 + (l_)) << 10) + rdoff))

  // prologue: tiles 0,1 in cadence order h0,h1,h2,h3 (2 gld_lds each)
  STB(rw, 0, 0); STB(rw + 4, 0, 0); STB(rw + 8, 0, 0); STB(rw + 12, 0, 0);
  STA(rw, 0, 0); STA(rw + 8, 0, 0); STA(rw + 4, 0, 0); STA(rw + 12, 0, 0);
  STB(rw, 1, 65536); STB(rw + 4, 1, 65536); STB(rw + 8, 1, 65536); STB(rw + 12, 1, 65536);
  STA(rw, 1, 65536); STA(rw + 8, 1, 65536); STA(rw + 4, 1, 65536); STA(rw + 12, 1, 65536);
  VM8(); BARRIER();                       // tile 0 landed (tile 1's 8 in flight)

  bf16x8 bC[8], aP[4], bN[8], aN[4];
  bC[0] = DSB_AT(0, 0, 0); bC[1] = DSB_AT(0, 0, 1); bC[2] = DSB_AT(0, 1, 0); bC[3] = DSB_AT(0, 1, 1);
  bC[4] = DSB_AT(0, 2, 0); bC[5] = DSB_AT(0, 2, 1); bC[6] = DSB_AT(0, 3, 0); bC[7] = DSB_AT(0, 3, 1);
  aP[0] = DSA_AT(0, 0, 0); aP[1] = DSA_AT(0, 0, 1); aP[2] = DSA_AT(0, 1, 0); aP[3] = DSA_AT(0, 1, 1);
  LGKM0(); BARRIER();                     // preload drained before ph1's h0(2) overwrite

#pragma unroll 2
  for (int kt = 0; kt < nKt; ++kt) {
    const int bufoff = (kt & 1) << 16;
    const int nbo = ((kt + 1) & 1) << 16;
    bf16x8 aQ[4];
    // ---- ph1: MFMA rows 0,1; read rows 2,3; stage h0(kt+2) ----
    aQ[0] = DSA_AT(bufoff, 2, 0); aQ[1] = DSA_AT(bufoff, 2, 1);
    aQ[2] = DSA_AT(bufoff, 3, 0); aQ[3] = DSA_AT(bufoff, 3, 1);
    if (kt + 2 < nKt) { STB(rw, kt + 2, bufoff); STB(rw + 4, kt + 2, bufoff); }
    SB0(); PRIO1(); MFMA16(0, 1, aP, bC); PRIO0(); LGKM0(); SB0(); BARRIER();
    // ---- ph2: MFMA rows 2,3; read rows 4,5; stage h1(kt+2) ----
    aP[0] = DSA_AT(bufoff, 4, 0); aP[1] = DSA_AT(bufoff, 4, 1);
    aP[2] = DSA_AT(bufoff, 5, 0); aP[3] = DSA_AT(bufoff, 5, 1);
    if (kt + 2 < nKt) { STB(rw + 8, kt + 2, bufoff); STB(rw + 12, kt + 2, bufoff); }
    SB0(); PRIO1(); MFMA16(2, 3, aQ, bC); PRIO0(); LGKM0(); SB0(); BARRIER();
    // ---- ph3: vmcnt; MFMA rows 4,5; read rows 6,7 + B[kt+1] half; stage h2(kt+2) ----
    if (kt + 1 < nKt) { if (kt + 2 < nKt) { VM4(); } else { VM0(); } }
    aQ[0] = DSA_AT(bufoff, 6, 0); aQ[1] = DSA_AT(bufoff, 6, 1);
    aQ[2] = DSA_AT(bufoff, 7, 0); aQ[3] = DSA_AT(bufoff, 7, 1);
    if (kt + 1 < nKt) {
      bN[0] = DSB_AT(nbo, 0, 0); bN[1] = DSB_AT(nbo, 0, 1);
      bN[2] = DSB_AT(nbo, 1, 0); bN[3] = DSB_AT(nbo, 1, 1);
    }
    if (kt + 2 < nKt) { STA(rw, kt + 2, bufoff); STA(rw + 8, kt + 2, bufoff); }
    SB0(); PRIO1(); MFMA16(4, 5, aP, bC); PRIO0(); LGKM0(); SB0(); BARRIER();
    // ---- ph4: MFMA rows 6,7; read B[kt+1] rest + A01[kt+1]; stage h3(kt+2) ----
    if (kt + 1 < nKt) {
      bN[4] = DSB_AT(nbo, 2, 0); bN[5] = DSB_AT(nbo, 2, 1);
      bN[6] = DSB_AT(nbo, 3, 0); bN[7] = DSB_AT(nbo, 3, 1);
      aN[0] = DSA_AT(nbo, 0, 0); aN[1] = DSA_AT(nbo, 0, 1);
      aN[2] = DSA_AT(nbo, 1, 0); aN[3] = DSA_AT(nbo, 1, 1);
    }
    if (kt + 2 < nKt) { STA(rw + 4, kt + 2, bufoff); STA(rw + 12, kt + 2, bufoff); }
    SB0(); PRIO1(); MFMA16(6, 7, aQ, bC); PRIO0(); LGKM0(); SB0(); BARRIER();
#pragma unroll
    for (int k = 0; k < 8; ++k) bC[k] = bN[k];
#pragma unroll
    for (int k = 0; k < 4; ++k) aP[k] = aN[k];
  }

  // epilogue: C/D layout col = lane&15, row = (lane>>4)*4 + reg
  const int crow = g * 4;
  const int rowB = sb * 256 + wm * 128, colB = tb * 256 + wn * 64;
#pragma unroll
  for (int i = 0; i < 8; ++i)
#pragma unroll
    for (int j = 0; j < 4; ++j) {
      const int col = colB + j * 16 + fr;
      if (col < ncols) {
#pragma unroll
        for (int rr = 0; rr < 4; ++rr)
          out[(size_t)(rowB + i * 16 + crow + rr) * ldc + col] = acc[i][j][rr];
      }
    }
}

extern "C" void kernel_launch(void* const* d_in, const int* in_sizes, int n_in,
                              void* d_out, int out_size, void* d_ws, size_t ws_size,
                              hipStream_t stream) {
  const float* h    = (const float*)d_in[0];
  const float* prot = (const float*)d_in[1];
  const float* pc   = (const float*)d_in[2];
  const float* temp = (const float*)d_in[3];
  float* out = (float*)d_out;

  const int D = 768;
  const int N = in_sizes[0] / D;          // 16384
  const int P = in_sizes[1] / D;          // 2048
  const int C = in_sizes[2] / P;          // 1000
  const int CP = (C + 127) & ~127;        // 1024 (padded)

  // workspace layout (16B aligned), all tiled
  char* ws = (char*)d_ws;
  size_t off = 0;
  uchar_t* h8   = (uchar_t*)(ws + off); off += (size_t)N * D;         // 12.6 MB fp8
  uchar_t* p8   = (uchar_t*)(ws + off); off += (size_t)P * D;         //  1.6 MB fp8
  ushort_t* pcT = (ushort_t*)(ws + off); off += (size_t)CP * P * 2;   //  4.2 MB bf16
  ushort_t* act = (ushort_t*)(ws + off); off += (size_t)N * P * 2;    // 67.1 MB bf16
  (void)ws_size;  // total ~85.5 MB

  // single prep dispatch: normalize (fp8 x4, tiled) + transpose (bf16, tiled)
  const int normBlocks = (N + P) / 4;                 // 4608
  const int transBlocks = (P / 32) * (CP / 32);       // 2048
  prep<<<normBlocks + transBlocks, 256, 0, stream>>>(
      (const float4*)h, h8, N, (const float4*)prot, p8, P,
      pc, pcT, P, C, normBlocks);

  // GEMM1: act[N,P](bf16 tiled) = epilogue(h8 @ p8^T), fp8, 256^2 lookahead pipeline
  {
    const int GX = P / 256, GY = N / 256;   // 8, 64 -> 512 blocks = 2/CU
    gemm1_fp8_la<<<GX * GY, 512, 0, stream>>>(h8, p8, act, temp, D / 64, P / 32, GX, 3);
  }
  // GEMM2: out[N,C](f32) = act @ pcT^T, bf16, 256^2 lookahead pipeline
  {
    const int GX = CP / 256, GY = N / 256;  // 4, 64  -> 256 blocks = 1/CU
    gemm2_bf16_la<<<GX * GY, 512, 0, stream>>>(act, pcT, out, C, C, P / 64);
  }
}

// Round 4
// 224.225 us; speedup vs baseline: 1.1733x; 1.1733x over previous
//
#include <hip/hip_runtime.h>
#include <hip/hip_bf16.h>
#include <math.h>

typedef unsigned short ushort_t;
typedef unsigned char uchar_t;
typedef unsigned int uint_t;
typedef __attribute__((ext_vector_type(8))) short bf16x8;   // 8 bf16 = 4 VGPRs
typedef __attribute__((ext_vector_type(4))) float f32x4;

#define AS1 __attribute__((address_space(1)))
#define AS3 __attribute__((address_space(3)))

__device__ __forceinline__ void gld_lds16(const void* g, void* l) {
  // async global->LDS, 16B per lane; LDS dest = wave-uniform base + lane*16
  __builtin_amdgcn_global_load_lds((const AS1 void*)g, (AS3 void*)l, 16, 0, 0);
}

__device__ __forceinline__ ushort_t f32_to_bf16_bits(float v) {
  __hip_bfloat16 b = __float2bfloat16(v);
  return *(ushort_t*)&b;
}

__device__ __forceinline__ uint_t pack_fp8x4(float4 v, float sc) {
  int r = __builtin_amdgcn_cvt_pk_fp8_f32(v.x * sc, v.y * sc, 0, false);
  r = __builtin_amdgcn_cvt_pk_fp8_f32(v.z * sc, v.w * sc, r, true);
  return (uint_t)r;
}

// ================= tiled operand layout =================
// Unit tile = 16 rows x 64 B, stored contiguously (1024 B). Tile index =
// rowblock * nKtiles + kt. Within a tile row rl, the 64 B is split into chunks
// XOR-permuted by a per-row key so MFMA fragment ds_reads are conflict-free:
//   fp8  (8-B chunks):  phys = logical ^ ((rl>>1)&7)   [R5: conflicts -> 0]
//   bf16 (16-B chunks): phys = logical ^ ((rl>>1)&3)   [2-way floor, free]
// global_load_lds copies tiles verbatim, so the LDS image equals the global image.

// ---------------- single prep kernel ----------------
__global__ __launch_bounds__(256) void prep(const float4* __restrict__ h,
                                            uchar_t* __restrict__ h8, int rowsH,
                                            const float4* __restrict__ p,
                                            uchar_t* __restrict__ p8, int rowsP,
                                            const float* __restrict__ pc,
                                            ushort_t* __restrict__ pcT,
                                            int P, int C, int normBlocks) {
  __shared__ float tile[32][33];
  if ((int)blockIdx.x < normBlocks) {
    int r = (blockIdx.x * 256 + threadIdx.x) >> 6;
    const int lane = threadIdx.x & 63;
    const float4* xr;
    uchar_t* o8;
    if (r < rowsH) {
      xr = h + (size_t)r * 192;          // 768 floats = 192 float4
      o8 = h8;
    } else {
      r -= rowsH;
      if (r >= rowsP) return;
      xr = p + (size_t)r * 192;
      o8 = p8;
    }
    float4 v0 = xr[lane];
    float4 v1 = xr[lane + 64];
    float4 v2 = xr[lane + 128];
    float ss = v0.x * v0.x + v0.y * v0.y + v0.z * v0.z + v0.w * v0.w
             + v1.x * v1.x + v1.y * v1.y + v1.z * v1.z + v1.w * v1.w
             + v2.x * v2.x + v2.y * v2.y + v2.z * v2.z + v2.w * v2.w;
#pragma unroll
    for (int off = 32; off > 0; off >>= 1) ss += __shfl_xor(ss, off, 64);
    const float sc = 4.0f / fmaxf(sqrtf(ss), 1e-12f);
    // lane L holds elements 4L..4L+3 of each 256-element group
    const int rb = r >> 4, rl = r & 15;
    const int key = (rl >> 1) & 7;
    const int cc = (lane & 15) >> 1;                  // logical 8-B chunk
    const int cphys = ((cc ^ key) << 3) + ((lane & 1) << 2);
    const int ktb = lane >> 4;                        // tile within group
    uchar_t* rowbase = o8 + (size_t)rb * 12 * 1024 + rl * 64 + cphys;
    *(uint_t*)(rowbase + (size_t)(ktb) * 1024)     = pack_fp8x4(v0, sc);
    *(uint_t*)(rowbase + (size_t)(4 + ktb) * 1024) = pack_fp8x4(v1, sc);
    *(uint_t*)(rowbase + (size_t)(8 + ktb) * 1024) = pack_fp8x4(v2, sc);
  } else {
    const int b = blockIdx.x - normBlocks;
    const int nkb = P / 32;                   // k-tiles per pcT row-block (=64)
    const int bk = b % nkb, bc = b / nkb;
    const int k0 = bk * 32, c0 = bc * 32;
    const int tx = threadIdx.x & 31, ty = threadIdx.x >> 5;   // ty 0..7
#pragma unroll
    for (int rr = 0; rr < 4; ++rr) {
      const int c = c0 + tx;
      tile[ty + rr * 8][tx] = (c < C) ? pc[(size_t)(k0 + ty + rr * 8) * C + c] : 0.f;
    }
    __syncthreads();
    const int c2 = tx >> 3, off = tx & 7;
#pragma unroll
    for (int rr = 0; rr < 4; ++rr) {
      const int row = c0 + ty + rr * 8;       // pcT row (class dim)
      const int rb = row >> 4, rl = row & 15;
      const int key4 = (rl >> 1) & 3;
      size_t us = (((size_t)rb * nkb + bk) * 16 + rl) * 32 + ((c2 ^ key4) << 3) + off;
      pcT[us] = f32_to_bf16_bits(tile[tx][ty + rr * 8]);
    }
  }
}

// ---------------- GEMM1: 128x128 fp8 MFMA, BK=128 (6 iters), tiled, XCD-swizzled ----------------
// act[N,P](bf16 tiled) = epilogue( h8 @ p8^T ), fp8 e4m3 scale x4 (acc = 16*dot).
// Known-good R0 structure; only change: sqrtf -> d2*rsqrtf (v_rsq) in epilogue.
__launch_bounds__(256)
__global__ void gemm1_fp8(const uchar_t* __restrict__ A, const uchar_t* __restrict__ B,
                          ushort_t* __restrict__ act, const float* __restrict__ tptr,
                          int nKt, int actKT, int gx, int gxlog2) {
  __shared__ __align__(16) uchar_t As[16384];   // 8 row-tiles x 2 k-tiles x 1 KB
  __shared__ __align__(16) uchar_t Bs[16384];
  const int tid = threadIdx.x, lane = tid & 63, wave = tid >> 6;
  const int wm = wave >> 1, wn = wave & 1;      // 2x2 wave grid, 64x64 each
  const int lid = blockIdx.x, xcd = lid & 7, q = lid >> 3;
  const int t = q & (gx - 1);
  const int s = ((q >> gxlog2) << 3) | xcd;

  f32x4 acc[4][4];
#pragma unroll
  for (int i = 0; i < 4; ++i)
#pragma unroll
    for (int j = 0; j < 4; ++j) acc[i][j] = (f32x4){0.f, 0.f, 0.f, 0.f};

  // staging: wave covers row-tiles {2w,2w+1} x k-tiles {2kt,2kt+1}; 1 KB per call
  const uchar_t* aW = A + ((size_t)(s * 8 + 2 * wave) * nKt) * 1024 + lane * 16;
  const uchar_t* bW = B + ((size_t)(t * 8 + 2 * wave) * nKt) * 1024 + lane * 16;
  const size_t rstride = (size_t)nKt * 1024;
  uchar_t* lA = &As[wave * 4096];
  uchar_t* lB = &Bs[wave * 4096];

  const int fr = lane & 15, g = lane >> 4;
  const int key = (fr >> 1) & 7;
  const int rowoff = fr * 64;
  const int cp0 = ((g ^ key) << 3);             // ksub=0: logical chunk g
  const int cp1 = (((g | 4) ^ key) << 3);       // ksub=1: logical chunk g+4

  const int nIter = nKt >> 1;                   // 6
  for (int kt = 0; kt < nIter; ++kt) {
    const size_t koff = (size_t)(2 * kt) * 1024;
    __syncthreads();  // previous tile's LDS reads done
    gld_lds16(aW + koff, lA);
    gld_lds16(aW + koff + 1024, lA + 1024);
    gld_lds16(aW + rstride + koff, lA + 2048);
    gld_lds16(aW + rstride + koff + 1024, lA + 3072);
    gld_lds16(bW + koff, lB);
    gld_lds16(bW + koff + 1024, lB + 1024);
    gld_lds16(bW + rstride + koff, lB + 2048);
    gld_lds16(bW + rstride + koff + 1024, lB + 3072);
    __syncthreads();  // staging complete

#pragma unroll
    for (int kk = 0; kk < 2; ++kk) {
#pragma unroll
      for (int ksub = 0; ksub < 2; ++ksub) {
        const int cp = ksub ? cp1 : cp0;
        long a[4], b[4];
#pragma unroll
        for (int i = 0; i < 4; ++i)
          a[i] = *(const long*)&As[((wm * 4 + i) * 2 + kk) * 1024 + rowoff + cp];
#pragma unroll
        for (int j = 0; j < 4; ++j)
          b[j] = *(const long*)&Bs[((wn * 4 + j) * 2 + kk) * 1024 + rowoff + cp];
#pragma unroll
        for (int i = 0; i < 4; ++i)
#pragma unroll
          for (int j = 0; j < 4; ++j)
            acc[i][j] = __builtin_amdgcn_mfma_f32_16x16x32_fp8_fp8(a[i], b[j], acc[i][j], 0, 0, 0);
      }
    }
  }

  float tmp = *tptr;
  const float tau = log1pf(expf(tmp));
  // C/D layout: col = lane&15, row = (lane>>4)*4 + reg   [measured m89/m91]
  const int crow = g * 4, ccol = fr;
  const int rowB = s * 128 + wm * 64, colB = t * 128 + wn * 64;
#pragma unroll
  for (int i = 0; i < 4; ++i)
#pragma unroll
    for (int j = 0; j < 4; ++j) {
      const int col = colB + j * 16 + ccol;
      const size_t ktile = col >> 5;
      const int c2 = (col >> 3) & 3, co = col & 7;
#pragma unroll
      for (int rr = 0; rr < 4; ++rr) {
        const int row = rowB + i * 16 + crow + rr;
        const int rb = row >> 4, rl = row & 15;
        const int key4 = (rl >> 1) & 3;
        float d2 = fmaxf(2.0f - acc[i][j][rr] * 0.125f, 0.0f);   // acc = 16*dot
        // sqrt via v_rsq: d2*rsqrt(d2); d2=0 -> 0 (clamped arg avoids 0*inf)
        float d = d2 * rsqrtf(fmaxf(d2, 1e-20f));
        float a = __expf(-tau * d);
        act[(((size_t)rb * actKT + ktile) * 16 + rl) * 32 + ((c2 ^ key4) << 3) + co] =
            f32_to_bf16_bits(a);
      }
    }
}

// ---------------- GEMM2: 256x256 bf16 MFMA, 8-phase counted-vmcnt, BALANCED reads ----------------
// out[N,C](f32) = act @ pcT^T.  BM=BN=256, BK=64, 8 waves (2Mx4N), per-wave 128x64.
// LDS 128 KiB = 2 dbuf x (A 32K + B 32K).  Same sync skeleton as R1 (verified 74us):
// per phase {reads | stage | BARRIER | LGKM0 | PRIO1 16xMFMA PRIO0 | [ph4 vmcnt] | BARRIER}.
// NEW: K-split MFMA mapping balances ds_reads 8/8/4/4 (was 12/4/4/4):
//   ph1: read A0-3.l0 + B.l0 (8) -> MFMA rows0-3 x l0
//   ph2: read A4-7.l0 + B.l1 (8) -> MFMA rows4-7 x l0   (B.l0 regs from ph1)
//   ph3: read A0-3.l1        (4) -> MFMA rows0-3 x l1   (B.l1 regs from ph2)
//   ph4: read A4-7.l1        (4) -> MFMA rows4-7 x l1
// Stage cadence (region proof): A-high(kt+1)@ph1 -> nbo (prev reads drained kt-1.ph4);
//   B0(kt+2)@ph3 -> bufoff B{0-7} (B[kt] reads drained at ph2; disjoint from ph3 reads);
//   B1+A-low(kt+2)@ph4 -> bufoff (B free; A-low drained at ph3; disjoint from ph4's A-high reads).
// vmcnt(6) at ph4: 6 newest = ph3(2)+ph4(4) stages; everything older (incl. ph1's
// A-high(kt+1) and (kt-1).ph3/4's B0/B1/A-low(kt+1)) drained -> tile kt+1 fully landed.
// Prologue: tile0 all 4 halves (8 calls, oldest) then tile1 B0,B1,A-low (6); VM6 drains
// tile0 completely (fixes R1's latent VM8 prologue hole).
#define BARRIER() do { asm volatile("" ::: "memory"); __builtin_amdgcn_s_barrier(); \
                       asm volatile("" ::: "memory"); } while (0)
#define LGKM0()   asm volatile("s_waitcnt lgkmcnt(0)" ::: "memory")
#define VM6()     asm volatile("s_waitcnt vmcnt(6)" ::: "memory")
#define VM0()     asm volatile("s_waitcnt vmcnt(0)" ::: "memory")
#define PRIO1()   __builtin_amdgcn_s_setprio(1)
#define PRIO0()   __builtin_amdgcn_s_setprio(0)
#define MM(a, b, c) __builtin_amdgcn_mfma_f32_16x16x32_bf16(a, b, c, 0, 0, 0)

// 16 MFMA: rows IB..IB+3 (A frags AT[0..3]) x cols 0..3 (B frags BL[0..3]);
// each acc element touched once per phase -> no intra-phase acc dependency.
#define MFMAQ(IB, AT, BL)                                          \
  acc[(IB) + 0][0] = MM(AT[0], BL[0], acc[(IB) + 0][0]);           \
  acc[(IB) + 1][0] = MM(AT[1], BL[0], acc[(IB) + 1][0]);           \
  acc[(IB) + 2][0] = MM(AT[2], BL[0], acc[(IB) + 2][0]);           \
  acc[(IB) + 3][0] = MM(AT[3], BL[0], acc[(IB) + 3][0]);           \
  acc[(IB) + 0][1] = MM(AT[0], BL[1], acc[(IB) + 0][1]);           \
  acc[(IB) + 1][1] = MM(AT[1], BL[1], acc[(IB) + 1][1]);           \
  acc[(IB) + 2][1] = MM(AT[2], BL[1], acc[(IB) + 2][1]);           \
  acc[(IB) + 3][1] = MM(AT[3], BL[1], acc[(IB) + 3][1]);           \
  acc[(IB) + 0][2] = MM(AT[0], BL[2], acc[(IB) + 0][2]);           \
  acc[(IB) + 1][2] = MM(AT[1], BL[2], acc[(IB) + 1][2]);           \
  acc[(IB) + 2][2] = MM(AT[2], BL[2], acc[(IB) + 2][2]);           \
  acc[(IB) + 3][2] = MM(AT[3], BL[2], acc[(IB) + 3][2]);           \
  acc[(IB) + 0][3] = MM(AT[0], BL[3], acc[(IB) + 0][3]);           \
  acc[(IB) + 1][3] = MM(AT[1], BL[3], acc[(IB) + 1][3]);           \
  acc[(IB) + 2][3] = MM(AT[2], BL[3], acc[(IB) + 2][3]);           \
  acc[(IB) + 3][3] = MM(AT[3], BL[3], acc[(IB) + 3][3])

__launch_bounds__(512, 2)
__global__ void gemm2_bf16_bal(const ushort_t* __restrict__ A,
                               const ushort_t* __restrict__ B,
                               float* __restrict__ out, int ldc, int ncols,
                               int nKt) {
  __shared__ __align__(16) uchar_t sm[131072];
  const int tid = threadIdx.x, lane = tid & 63, wave = tid >> 6;   // 8 waves
  const int wm = wave >> 2, wn = wave & 3;                         // 2M x 4N
  const int lid = blockIdx.x, xcd = lid & 7, q = lid >> 3;
  const int tb = q & 3, sb = ((q >> 2) << 3) | xcd;   // col-tile 0..3, row-tile 0..63

  f32x4 acc[8][4];
#pragma unroll
  for (int i = 0; i < 8; ++i)
#pragma unroll
    for (int j = 0; j < 4; ++j) acc[i][j] = (f32x4){0.f, 0.f, 0.f, 0.f};

  // stage-role: wave pair rw = wave>>1 covers row-blocks {rw, rw+4, rw+8, rw+12},
  // lw = wave&1 selects the unit-k (l) within the K-tile.
  const int lw = wave & 1, rw = wave >> 1;
  const uchar_t* Apl = (const uchar_t*)A + ((size_t)(sb * 16) << 16) + (lw << 10) + lane * 16;
  const uchar_t* Bpl = (const uchar_t*)B + ((size_t)(tb * 16) << 16) + (lw << 10) + lane * 16;

  // ds_read per-lane offset within a unit tile (16-B chunk XOR key)
  const int fr = lane & 15, g = lane >> 4;
  const int rdoff = fr * 64 + ((g ^ ((fr >> 1) & 3)) << 4);
  const int wm8 = wm * 8, wn4 = wn * 4;

#define STA(r_, T_, bo_) gld_lds16(Apl + (((size_t)(r_) << 16) + ((size_t)(T_) << 11)), \
                                   sm + (bo_) + ((((r_) << 1) + lw) << 10))
#define STB(r_, T_, bo_) gld_lds16(Bpl + (((size_t)(r_) << 16) + ((size_t)(T_) << 11)), \
                                   sm + (bo_) + 32768 + ((((r_) << 1) + lw) << 10))
#define DSA(i_, l_) (*(const bf16x8*)(sm + bufoff + (((wm8 + (i_)) * 2 + (l_)) << 10) + rdoff))
#define DSB(j_, l_) (*(const bf16x8*)(sm + bufoff + 32768 + (((wn4 + (j_)) * 2 + (l_)) << 10) + rdoff))

  // prologue: tile0 fully (8 calls, oldest: B0,B1,A-low,A-high), tile1 B0,B1,A-low (6)
  STB(rw, 0, 0); STB(rw + 4, 0, 0); STB(rw + 8, 0, 0); STB(rw + 12, 0, 0);
  STA(rw, 0, 0); STA(rw + 8, 0, 0); STA(rw + 4, 0, 0); STA(rw + 12, 0, 0);
  STB(rw, 1, 65536); STB(rw + 4, 1, 65536); STB(rw + 8, 1, 65536); STB(rw + 12, 1, 65536);
  STA(rw, 1, 65536); STA(rw + 8, 1, 65536);
  VM6(); BARRIER();   // tile 0 fully landed; tile 1's 6 remain in flight

  bf16x8 at[4], bl0[4], bl1[4];
  for (int kt = 0; kt < nKt; ++kt) {
    const int bufoff = (kt & 1) << 16;
    const int nbo = ((kt + 1) & 1) << 16;
    // ---------- ph1: read A0-3.l0 + B.l0 (8); stage A-high(kt+1) -> nbo ----------
    at[0] = DSA(0, 0); at[1] = DSA(1, 0); at[2] = DSA(2, 0); at[3] = DSA(3, 0);
    bl0[0] = DSB(0, 0); bl0[1] = DSB(1, 0); bl0[2] = DSB(2, 0); bl0[3] = DSB(3, 0);
    if (kt + 1 < nKt) { STA(rw + 4, kt + 1, nbo); STA(rw + 12, kt + 1, nbo); }
    BARRIER(); LGKM0();
    PRIO1(); MFMAQ(0, at, bl0); PRIO0();
    BARRIER();
    // ---------- ph2: read A4-7.l0 + B.l1 (8); no stage ----------
    at[0] = DSA(4, 0); at[1] = DSA(5, 0); at[2] = DSA(6, 0); at[3] = DSA(7, 0);
    bl1[0] = DSB(0, 1); bl1[1] = DSB(1, 1); bl1[2] = DSB(2, 1); bl1[3] = DSB(3, 1);
    BARRIER(); LGKM0();
    PRIO1(); MFMAQ(4, at, bl0); PRIO0();
    BARRIER();
    // ---------- ph3: read A0-3.l1 (4); stage B0(kt+2) -> bufoff ----------
    at[0] = DSA(0, 1); at[1] = DSA(1, 1); at[2] = DSA(2, 1); at[3] = DSA(3, 1);
    if (kt + 2 < nKt) { STB(rw, kt + 2, bufoff); STB(rw + 4, kt + 2, bufoff); }
    BARRIER(); LGKM0();
    PRIO1(); MFMAQ(0, at, bl1); PRIO0();
    BARRIER();
    // ---------- ph4: read A4-7.l1 (4); stage B1+A-low(kt+2) -> bufoff; counted vmcnt ----------
    at[0] = DSA(4, 1); at[1] = DSA(5, 1); at[2] = DSA(6, 1); at[3] = DSA(7, 1);
    if (kt + 2 < nKt) {
      STB(rw + 8, kt + 2, bufoff); STB(rw + 12, kt + 2, bufoff);
      STA(rw, kt + 2, bufoff);     STA(rw + 8, kt + 2, bufoff);
    }
    BARRIER(); LGKM0();
    PRIO1(); MFMAQ(4, at, bl1); PRIO0();
    if (kt + 2 < nKt) { VM6(); } else { VM0(); }
    BARRIER();
  }

  // epilogue: C/D layout col = lane&15, row = (lane>>4)*4 + reg
  const int crow = g * 4;
  const int rowB = sb * 256 + wm * 128, colB = tb * 256 + wn * 64;
#pragma unroll
  for (int i = 0; i < 8; ++i)
#pragma unroll
    for (int j = 0; j < 4; ++j) {
      const int col = colB + j * 16 + fr;
      if (col < ncols) {
#pragma unroll
        for (int rr = 0; rr < 4; ++rr)
          out[(size_t)(rowB + i * 16 + crow + rr) * ldc + col] = acc[i][j][rr];
      }
    }
}

extern "C" void kernel_launch(void* const* d_in, const int* in_sizes, int n_in,
                              void* d_out, int out_size, void* d_ws, size_t ws_size,
                              hipStream_t stream) {
  const float* h    = (const float*)d_in[0];
  const float* prot = (const float*)d_in[1];
  const float* pc   = (const float*)d_in[2];
  const float* temp = (const float*)d_in[3];
  float* out = (float*)d_out;

  const int D = 768;
  const int N = in_sizes[0] / D;          // 16384
  const int P = in_sizes[1] / D;          // 2048
  const int C = in_sizes[2] / P;          // 1000
  const int CP = (C + 127) & ~127;        // 1024 (padded)

  // workspace layout (16B aligned), all tiled
  char* ws = (char*)d_ws;
  size_t off = 0;
  uchar_t* h8   = (uchar_t*)(ws + off); off += (size_t)N * D;         // 12.6 MB fp8
  uchar_t* p8   = (uchar_t*)(ws + off); off += (size_t)P * D;         //  1.6 MB fp8
  ushort_t* pcT = (ushort_t*)(ws + off); off += (size_t)CP * P * 2;   //  4.2 MB bf16
  ushort_t* act = (ushort_t*)(ws + off); off += (size_t)N * P * 2;    // 67.1 MB bf16
  (void)ws_size;  // total ~85.5 MB

  // single prep dispatch: normalize (fp8 x4, tiled) + transpose (bf16, tiled)
  const int normBlocks = (N + P) / 4;                 // 4608
  const int transBlocks = (P / 32) * (CP / 32);       // 2048
  prep<<<normBlocks + transBlocks, 256, 0, stream>>>(
      (const float4*)h, h8, N, (const float4*)prot, p8, P,
      pc, pcT, P, C, normBlocks);

  // GEMM1: act[N,P](bf16 tiled) = epilogue(h8 @ p8^T), fp8, BK=128 (known-good 128^2)
  {
    const int GX = P / 128, GY = N / 128;   // 16, 128
    gemm1_fp8<<<GX * GY, 256, 0, stream>>>(h8, p8, act, temp, D / 64, P / 32, GX, 4);
  }
  // GEMM2: out[N,C](f32) = act @ pcT^T, bf16, 256^2 8-phase balanced reads
  {
    const int GX = CP / 256, GY = N / 256;  // 4, 64  -> 256 blocks = 1/CU
    gemm2_bf16_bal<<<GX * GY, 512, 0, stream>>>(act, pcT, out, C, C, P / 64);
  }
}

// Round 7
// 222.493 us; speedup vs baseline: 1.1824x; 1.0078x over previous
//
#include <hip/hip_runtime.h>
#include <hip/hip_bf16.h>
#include <math.h>

typedef unsigned short ushort_t;
typedef unsigned char uchar_t;
typedef unsigned int uint_t;
typedef __attribute__((ext_vector_type(8))) short bf16x8;   // 8 bf16 = 4 VGPRs
typedef __attribute__((ext_vector_type(4))) float f32x4;

#define AS1 __attribute__((address_space(1)))
#define AS3 __attribute__((address_space(3)))

__device__ __forceinline__ void gld_lds16(const void* g, void* l) {
  // async global->LDS, 16B per lane; LDS dest = wave-uniform base + lane*16
  __builtin_amdgcn_global_load_lds((const AS1 void*)g, (AS3 void*)l, 16, 0, 0);
}

__device__ __forceinline__ ushort_t f32_to_bf16_bits(float v) {
  __hip_bfloat16 b = __float2bfloat16(v);
  return *(ushort_t*)&b;
}

__device__ __forceinline__ uint_t pack_fp8x4(float4 v, float sc) {
  int r = __builtin_amdgcn_cvt_pk_fp8_f32(v.x * sc, v.y * sc, 0, false);
  r = __builtin_amdgcn_cvt_pk_fp8_f32(v.z * sc, v.w * sc, r, true);
  return (uint_t)r;
}

// ================= tiled operand layout =================
// Unit tile = 16 rows x 64 B, stored contiguously (1024 B). Tile index =
// rowblock * nKtiles + kt. Within a tile row rl, the 64 B is split into chunks
// XOR-permuted by a per-row key so MFMA fragment ds_reads are conflict-free:
//   fp8  (8-B chunks):  phys = logical ^ ((rl>>1)&7)
//   bf16 (16-B chunks): phys = logical ^ ((rl>>1)&3)
// global_load_lds copies tiles verbatim, so the LDS image equals the global image.

// ---------------- single prep kernel ----------------
__global__ __launch_bounds__(256) void prep(const float4* __restrict__ h,
                                            uchar_t* __restrict__ h8, int rowsH,
                                            const float4* __restrict__ p,
                                            uchar_t* __restrict__ p8, int rowsP,
                                            const float* __restrict__ pc,
                                            ushort_t* __restrict__ pcT,
                                            int P, int C, int normBlocks) {
  __shared__ float tile[32][33];
  if ((int)blockIdx.x < normBlocks) {
    int r = (blockIdx.x * 256 + threadIdx.x) >> 6;
    const int lane = threadIdx.x & 63;
    const float4* xr;
    uchar_t* o8;
    if (r < rowsH) {
      xr = h + (size_t)r * 192;          // 768 floats = 192 float4
      o8 = h8;
    } else {
      r -= rowsH;
      if (r >= rowsP) return;
      xr = p + (size_t)r * 192;
      o8 = p8;
    }
    float4 v0 = xr[lane];
    float4 v1 = xr[lane + 64];
    float4 v2 = xr[lane + 128];
    float ss = v0.x * v0.x + v0.y * v0.y + v0.z * v0.z + v0.w * v0.w
             + v1.x * v1.x + v1.y * v1.y + v1.z * v1.z + v1.w * v1.w
             + v2.x * v2.x + v2.y * v2.y + v2.z * v2.z + v2.w * v2.w;
#pragma unroll
    for (int off = 32; off > 0; off >>= 1) ss += __shfl_xor(ss, off, 64);
    const float sc = 4.0f / fmaxf(sqrtf(ss), 1e-12f);
    // lane L holds elements 4L..4L+3 of each 256-element group
    const int rb = r >> 4, rl = r & 15;
    const int key = (rl >> 1) & 7;
    const int cc = (lane & 15) >> 1;                  // logical 8-B chunk
    const int cphys = ((cc ^ key) << 3) + ((lane & 1) << 2);
    const int ktb = lane >> 4;                        // tile within group
    uchar_t* rowbase = o8 + (size_t)rb * 12 * 1024 + rl * 64 + cphys;
    *(uint_t*)(rowbase + (size_t)(ktb) * 1024)     = pack_fp8x4(v0, sc);
    *(uint_t*)(rowbase + (size_t)(4 + ktb) * 1024) = pack_fp8x4(v1, sc);
    *(uint_t*)(rowbase + (size_t)(8 + ktb) * 1024) = pack_fp8x4(v2, sc);
  } else {
    const int b = blockIdx.x - normBlocks;
    const int nkb = P / 32;                   // k-tiles per pcT row-block (=64)
    const int bk = b % nkb, bc = b / nkb;
    const int k0 = bk * 32, c0 = bc * 32;
    const int tx = threadIdx.x & 31, ty = threadIdx.x >> 5;   // ty 0..7
#pragma unroll
    for (int rr = 0; rr < 4; ++rr) {
      const int c = c0 + tx;
      tile[ty + rr * 8][tx] = (c < C) ? pc[(size_t)(k0 + ty + rr * 8) * C + c] : 0.f;
    }
    __syncthreads();
    const int c2 = tx >> 3, off = tx & 7;
#pragma unroll
    for (int rr = 0; rr < 4; ++rr) {
      const int row = c0 + ty + rr * 8;       // pcT row (class dim)
      const int rb = row >> 4, rl = row & 15;
      const int key4 = (rl >> 1) & 3;
      size_t us = (((size_t)rb * nkb + bk) * 16 + rl) * 32 + ((c2 ^ key4) << 3) + off;
      pcT[us] = f32_to_bf16_bits(tile[tx][ty + rr * 8]);
    }
  }
}

// ---------------- GEMM1: 128x128 fp8 MFMA, BK=128 (6 iters), tiled, XCD-swizzled ----------------
// act[N,P](bf16 tiled) = epilogue( h8 @ p8^T ), fp8 e4m3 scale x4 (acc = 16*dot).
// Known-good R0 structure + rsqrt epilogue (R4, verified passing).
__launch_bounds__(256)
__global__ void gemm1_fp8(const uchar_t* __restrict__ A, const uchar_t* __restrict__ B,
                          ushort_t* __restrict__ act, const float* __restrict__ tptr,
                          int nKt, int actKT, int gx, int gxlog2) {
  __shared__ __align__(16) uchar_t As[16384];   // 8 row-tiles x 2 k-tiles x 1 KB
  __shared__ __align__(16) uchar_t Bs[16384];
  const int tid = threadIdx.x, lane = tid & 63, wave = tid >> 6;
  const int wm = wave >> 1, wn = wave & 1;      // 2x2 wave grid, 64x64 each
  const int lid = blockIdx.x, xcd = lid & 7, q = lid >> 3;
  const int t = q & (gx - 1);
  const int s = ((q >> gxlog2) << 3) | xcd;

  f32x4 acc[4][4];
#pragma unroll
  for (int i = 0; i < 4; ++i)
#pragma unroll
    for (int j = 0; j < 4; ++j) acc[i][j] = (f32x4){0.f, 0.f, 0.f, 0.f};

  // staging: wave covers row-tiles {2w,2w+1} x k-tiles {2kt,2kt+1}; 1 KB per call
  const uchar_t* aW = A + ((size_t)(s * 8 + 2 * wave) * nKt) * 1024 + lane * 16;
  const uchar_t* bW = B + ((size_t)(t * 8 + 2 * wave) * nKt) * 1024 + lane * 16;
  const size_t rstride = (size_t)nKt * 1024;
  uchar_t* lA = &As[wave * 4096];
  uchar_t* lB = &Bs[wave * 4096];

  const int fr = lane & 15, g = lane >> 4;
  const int key = (fr >> 1) & 7;
  const int rowoff = fr * 64;
  const int cp0 = ((g ^ key) << 3);             // ksub=0: logical chunk g
  const int cp1 = (((g | 4) ^ key) << 3);       // ksub=1: logical chunk g+4

  const int nIter = nKt >> 1;                   // 6
  for (int kt = 0; kt < nIter; ++kt) {
    const size_t koff = (size_t)(2 * kt) * 1024;
    __syncthreads();  // previous tile's LDS reads done
    gld_lds16(aW + koff, lA);
    gld_lds16(aW + koff + 1024, lA + 1024);
    gld_lds16(aW + rstride + koff, lA + 2048);
    gld_lds16(aW + rstride + koff + 1024, lA + 3072);
    gld_lds16(bW + koff, lB);
    gld_lds16(bW + koff + 1024, lB + 1024);
    gld_lds16(bW + rstride + koff, lB + 2048);
    gld_lds16(bW + rstride + koff + 1024, lB + 3072);
    __syncthreads();  // staging complete

#pragma unroll
    for (int kk = 0; kk < 2; ++kk) {
#pragma unroll
      for (int ksub = 0; ksub < 2; ++ksub) {
        const int cp = ksub ? cp1 : cp0;
        long a[4], b[4];
#pragma unroll
        for (int i = 0; i < 4; ++i)
          a[i] = *(const long*)&As[((wm * 4 + i) * 2 + kk) * 1024 + rowoff + cp];
#pragma unroll
        for (int j = 0; j < 4; ++j)
          b[j] = *(const long*)&Bs[((wn * 4 + j) * 2 + kk) * 1024 + rowoff + cp];
#pragma unroll
        for (int i = 0; i < 4; ++i)
#pragma unroll
          for (int j = 0; j < 4; ++j)
            acc[i][j] = __builtin_amdgcn_mfma_f32_16x16x32_fp8_fp8(a[i], b[j], acc[i][j], 0, 0, 0);
      }
    }
  }

  float tmp = *tptr;
  const float tau = log1pf(expf(tmp));
  // C/D layout: col = lane&15, row = (lane>>4)*4 + reg   [measured m89/m91]
  const int crow = g * 4, ccol = fr;
  const int rowB = s * 128 + wm * 64, colB = t * 128 + wn * 64;
#pragma unroll
  for (int i = 0; i < 4; ++i)
#pragma unroll
    for (int j = 0; j < 4; ++j) {
      const int col = colB + j * 16 + ccol;
      const size_t ktile = col >> 5;
      const int c2 = (col >> 3) & 3, co = col & 7;
#pragma unroll
      for (int rr = 0; rr < 4; ++rr) {
        const int row = rowB + i * 16 + crow + rr;
        const int rb = row >> 4, rl = row & 15;
        const int key4 = (rl >> 1) & 3;
        float d2 = fmaxf(2.0f - acc[i][j][rr] * 0.125f, 0.0f);   // acc = 16*dot
        // sqrt via v_rsq: d2*rsqrt(d2); d2=0 -> 0 (clamped arg avoids 0*inf)
        float d = d2 * rsqrtf(fmaxf(d2, 1e-20f));
        float a = __expf(-tau * d);
        act[(((size_t)rb * actKT + ktile) * 16 + rl) * 32 + ((c2 ^ key4) << 3) + co] =
            f32_to_bf16_bits(a);
      }
    }
}

// ---------------- GEMM2: 256x256 bf16 MFMA, 8-phase counted-vmcnt schedule ----------------
// R1-verified structure (74.2 us, passed twice).  out[N,C](f32) = act @ pcT^T.
// BM=BN=256, BK=64, 8 waves (2Mx4N), per-wave 128x64.
// LDS 128 KiB = 2 dbuf x (A 32K + B 32K); K-tile = 32 unit tiles per operand.
// Per K-tile: 4 phases {ds_read (A-pair; +all B in ph1) | stage 1 half-tile (2 gld/wave)
//   | barrier | lgkmcnt(0) | setprio(1) 16 MFMA setprio(0) | [ph4: vmcnt(6)] | barrier}.
// Half-tile issue order for tile T: h0=B[0-7] @T-2.ph2, h1=B[8-15] @T-2.ph3,
//   h2=A{0-3,8-11} @T-2.ph4, h3=A{4-7,12-15} @T-1.ph1.  vmcnt(6) at ph4 = 3 half-tiles
//   in flight -> tile T+1 fully landed.
#define BARRIER() do { asm volatile("" ::: "memory"); __builtin_amdgcn_s_barrier(); \
                       asm volatile("" ::: "memory"); } while (0)
#define LGKM0()   asm volatile("s_waitcnt lgkmcnt(0)" ::: "memory")
#define VM6()     asm volatile("s_waitcnt vmcnt(6)" ::: "memory")
#define VM0()     asm volatile("s_waitcnt vmcnt(0)" ::: "memory")
#define PRIO1()   __builtin_amdgcn_s_setprio(1)
#define PRIO0()   __builtin_amdgcn_s_setprio(0)
#define MM(a, b, c) __builtin_amdgcn_mfma_f32_16x16x32_bf16(a, b, c, 0, 0, 0)

// 16 MFMA for fragment rows I0,I1 over K=64 (l=0 then l=1; same-acc distance 8)
#define PHASE_MFMA(I0, I1, A00, A01, A10, A11)                                   \
  acc[I0][0] = MM(A00, b00, acc[I0][0]); acc[I0][1] = MM(A00, b10, acc[I0][1]);  \
  acc[I0][2] = MM(A00, b20, acc[I0][2]); acc[I0][3] = MM(A00, b30, acc[I0][3]);  \
  acc[I1][0] = MM(A10, b00, acc[I1][0]); acc[I1][1] = MM(A10, b10, acc[I1][1]);  \
  acc[I1][2] = MM(A10, b20, acc[I1][2]); acc[I1][3] = MM(A10, b30, acc[I1][3]);  \
  acc[I0][0] = MM(A01, b01, acc[I0][0]); acc[I0][1] = MM(A01, b11, acc[I0][1]);  \
  acc[I0][2] = MM(A01, b21, acc[I0][2]); acc[I0][3] = MM(A01, b31, acc[I0][3]);  \
  acc[I1][0] = MM(A11, b01, acc[I1][0]); acc[I1][1] = MM(A11, b11, acc[I1][1]);  \
  acc[I1][2] = MM(A11, b21, acc[I1][2]); acc[I1][3] = MM(A11, b31, acc[I1][3])

__launch_bounds__(512, 2)
__global__ void gemm2_bf16_8ph(const ushort_t* __restrict__ A,
                               const ushort_t* __restrict__ B,
                               float* __restrict__ out, int ldc, int ncols,
                               int nKt) {
  __shared__ __align__(16) uchar_t sm[131072];
  const int tid = threadIdx.x, lane = tid & 63, wave = tid >> 6;   // 8 waves
  const int wm = wave >> 2, wn = wave & 3;                         // 2M x 4N
  const int lid = blockIdx.x, xcd = lid & 7, q = lid >> 3;
  const int tb = q & 3, sb = ((q >> 2) << 3) | xcd;   // col-tile 0..3, row-tile 0..63

  f32x4 acc[8][4];
#pragma unroll
  for (int i = 0; i < 8; ++i)
#pragma unroll
    for (int j = 0; j < 4; ++j) acc[i][j] = (f32x4){0.f, 0.f, 0.f, 0.f};

  // stage-role: wave pair rw = wave>>1 covers row-blocks {rw, rw+4, rw+8, rw+12},
  // lw = wave&1 selects the unit-k (l) within the K-tile.
  const int lw = wave & 1, rw = wave >> 1;
  const uchar_t* Apl = (const uchar_t*)A + ((size_t)(sb * 16) << 16) + (lw << 10) + lane * 16;
  const uchar_t* Bpl = (const uchar_t*)B + ((size_t)(tb * 16) << 16) + (lw << 10) + lane * 16;

  // ds_read per-lane offset within a unit tile (16-B chunk XOR key)
  const int fr = lane & 15, g = lane >> 4;
  const int rdoff = fr * 64 + ((g ^ ((fr >> 1) & 3)) << 4);
  const int wm8 = wm * 8, wn4 = wn * 4;

#define STA(r_, T_, bo_) gld_lds16(Apl + (((size_t)(r_) << 16) + ((size_t)(T_) << 11)), \
                                   sm + (bo_) + ((((r_) << 1) + lw) << 10))
#define STB(r_, T_, bo_) gld_lds16(Bpl + (((size_t)(r_) << 16) + ((size_t)(T_) << 11)), \
                                   sm + (bo_) + 32768 + ((((r_) << 1) + lw) << 10))
#define DSA(i_, l_) (*(const bf16x8*)(sm + bufoff + (((wm8 + (i_)) * 2 + (l_)) << 10) + rdoff))
#define DSB(j_, l_) (*(const bf16x8*)(sm + bufoff + 32768 + (((wn4 + (j_)) * 2 + (l_)) << 10) + rdoff))

  // prologue: tile 0 fully (8 calls, oldest), tile 1 h0..h2 (6 calls)
  STB(rw, 0, 0); STB(rw + 4, 0, 0); STB(rw + 8, 0, 0); STB(rw + 12, 0, 0);
  STA(rw, 0, 0); STA(rw + 8, 0, 0); STA(rw + 4, 0, 0); STA(rw + 12, 0, 0);
  STB(rw, 1, 65536); STB(rw + 4, 1, 65536); STB(rw + 8, 1, 65536); STB(rw + 12, 1, 65536);
  STA(rw, 1, 65536); STA(rw + 8, 1, 65536);
  VM6(); BARRIER();

  for (int kt = 0; kt < nKt; ++kt) {
    const int bufoff = (kt & 1) << 16;
    const int nbo = ((kt + 1) & 1) << 16;
    // ---------- phase 1: all B + A rows 0,1 (12 reads); stage (kt+1) h3 ----------
    bf16x8 b00 = DSB(0, 0), b01 = DSB(0, 1), b10 = DSB(1, 0), b11 = DSB(1, 1);
    bf16x8 b20 = DSB(2, 0), b21 = DSB(2, 1), b30 = DSB(3, 0), b31 = DSB(3, 1);
    bf16x8 a00 = DSA(0, 0), a01 = DSA(0, 1), a10 = DSA(1, 0), a11 = DSA(1, 1);
    if (kt + 1 < nKt) { STA(rw + 4, kt + 1, nbo); STA(rw + 12, kt + 1, nbo); }
    BARRIER(); LGKM0();
    PRIO1();
    PHASE_MFMA(0, 1, a00, a01, a10, a11);
    PRIO0();
    BARRIER();
    // ---------- phase 2: A rows 2,3; stage (kt+2) h0 = B[0-7] ----------
    {
      bf16x8 a20 = DSA(2, 0), a21 = DSA(2, 1), a30 = DSA(3, 0), a31 = DSA(3, 1);
      if (kt + 2 < nKt) { STB(rw, kt + 2, bufoff); STB(rw + 4, kt + 2, bufoff); }
      BARRIER(); LGKM0();
      PRIO1();
      PHASE_MFMA(2, 3, a20, a21, a30, a31);
      PRIO0();
      BARRIER();
    }
    // ---------- phase 3: A rows 4,5; stage (kt+2) h1 = B[8-15] ----------
    {
      bf16x8 a40 = DSA(4, 0), a41 = DSA(4, 1), a50 = DSA(5, 0), a51 = DSA(5, 1);
      if (kt + 2 < nKt) { STB(rw + 8, kt + 2, bufoff); STB(rw + 12, kt + 2, bufoff); }
      BARRIER(); LGKM0();
      PRIO1();
      PHASE_MFMA(4, 5, a40, a41, a50, a51);
      PRIO0();
      BARRIER();
    }
    // ---------- phase 4: A rows 6,7; stage (kt+2) h2 = A{0-3,8-11}; counted vmcnt ----------
    {
      bf16x8 a60 = DSA(6, 0), a61 = DSA(6, 1), a70 = DSA(7, 0), a71 = DSA(7, 1);
      if (kt + 2 < nKt) { STA(rw, kt + 2, bufoff); STA(rw + 8, kt + 2, bufoff); }
      BARRIER(); LGKM0();
      PRIO1();
      PHASE_MFMA(6, 7, a60, a61, a70, a71);
      PRIO0();
      if (kt + 2 < nKt) { VM6(); } else { VM0(); }
      BARRIER();
    }
  }

  // epilogue: C/D layout col = lane&15, row = (lane>>4)*4 + reg
  const int crow = g * 4;
  const int rowB = sb * 256 + wm * 128, colB = tb * 256 + wn * 64;
#pragma unroll
  for (int i = 0; i < 8; ++i)
#pragma unroll
    for (int j = 0; j < 4; ++j) {
      const int col = colB + j * 16 + fr;
      if (col < ncols) {
#pragma unroll
        for (int rr = 0; rr < 4; ++rr)
          out[(size_t)(rowB + i * 16 + crow + rr) * ldc + col] = acc[i][j][rr];
      }
    }
}

extern "C" void kernel_launch(void* const* d_in, const int* in_sizes, int n_in,
                              void* d_out, int out_size, void* d_ws, size_t ws_size,
                              hipStream_t stream) {
  const float* h    = (const float*)d_in[0];
  const float* prot = (const float*)d_in[1];
  const float* pc   = (const float*)d_in[2];
  const float* temp = (const float*)d_in[3];
  float* out = (float*)d_out;

  const int D = 768;
  const int N = in_sizes[0] / D;          // 16384
  const int P = in_sizes[1] / D;          // 2048
  const int C = in_sizes[2] / P;          // 1000
  const int CP = (C + 127) & ~127;        // 1024 (padded)

  // workspace layout (16B aligned), all tiled
  char* ws = (char*)d_ws;
  size_t off = 0;
  uchar_t* h8   = (uchar_t*)(ws + off); off += (size_t)N * D;         // 12.6 MB fp8
  uchar_t* p8   = (uchar_t*)(ws + off); off += (size_t)P * D;         //  1.6 MB fp8
  ushort_t* pcT = (ushort_t*)(ws + off); off += (size_t)CP * P * 2;   //  4.2 MB bf16
  ushort_t* act = (ushort_t*)(ws + off); off += (size_t)N * P * 2;    // 67.1 MB bf16
  (void)ws_size;  // total ~85.5 MB

  // single prep dispatch: normalize (fp8 x4, tiled) + transpose (bf16, tiled)
  const int normBlocks = (N + P) / 4;                 // 4608
  const int transBlocks = (P / 32) * (CP / 32);       // 2048
  prep<<<normBlocks + transBlocks, 256, 0, stream>>>(
      (const float4*)h, h8, N, (const float4*)prot, p8, P,
      pc, pcT, P, C, normBlocks);

  // GEMM1: act[N,P](bf16 tiled) = epilogue(h8 @ p8^T), fp8, BK=128 (known-good 128^2)
  {
    const int GX = P / 128, GY = N / 128;   // 16, 128
    gemm1_fp8<<<GX * GY, 256, 0, stream>>>(h8, p8, act, temp, D / 64, P / 32, GX, 4);
  }
  // GEMM2: out[N,C](f32) = act @ pcT^T, bf16, 256^2 8-phase counted-vmcnt (R1-verified)
  {
    const int GX = CP / 256, GY = N / 256;  // 4, 64  -> 256 blocks = 1/CU
    gemm2_bf16_8ph<<<GX * GY, 512, 0, stream>>>(act, pcT, out, C, C, P / 64);
  }
}

// Round 9
// 216.971 us; speedup vs baseline: 1.2125x; 1.0255x over previous
//
#include <hip/hip_runtime.h>
#include <hip/hip_bf16.h>
#include <math.h>

typedef unsigned short ushort_t;
typedef unsigned char uchar_t;
typedef unsigned int uint_t;
typedef __attribute__((ext_vector_type(8))) short bf16x8;   // 8 bf16 = 4 VGPRs
typedef __attribute__((ext_vector_type(4))) float f32x4;

#define AS1 __attribute__((address_space(1)))
#define AS3 __attribute__((address_space(3)))

__device__ __forceinline__ void gld_lds16(const void* g, void* l) {
  // async global->LDS, 16B per lane; LDS dest = wave-uniform base + lane*16
  __builtin_amdgcn_global_load_lds((const AS1 void*)g, (AS3 void*)l, 16, 0, 0);
}

__device__ __forceinline__ ushort_t f32_to_bf16_bits(float v) {
  __hip_bfloat16 b = __float2bfloat16(v);
  return *(ushort_t*)&b;
}

__device__ __forceinline__ uint_t pack_fp8x4(float4 v, float sc) {
  int r = __builtin_amdgcn_cvt_pk_fp8_f32(v.x * sc, v.y * sc, 0, false);
  r = __builtin_amdgcn_cvt_pk_fp8_f32(v.z * sc, v.w * sc, r, true);
  return (uint_t)r;
}

// ================= tiled operand layout =================
// Unit tile = 16 rows x 64 B, stored contiguously (1024 B). Tile index =
// rowblock * nKtiles + kt. Within a tile row rl, the 64 B is split into chunks
// XOR-permuted by a per-row key so MFMA fragment ds_reads are conflict-free:
//   fp8  (8-B chunks):  phys = logical ^ ((rl>>1)&7)
//   bf16 (16-B chunks): phys = logical ^ ((rl>>1)&3)
// global_load_lds copies tiles verbatim, so the LDS image equals the global image.

// ---------------- single prep kernel ----------------
__global__ __launch_bounds__(256) void prep(const float4* __restrict__ h,
                                            uchar_t* __restrict__ h8, int rowsH,
                                            const float4* __restrict__ p,
                                            uchar_t* __restrict__ p8, int rowsP,
                                            const float* __restrict__ pc,
                                            ushort_t* __restrict__ pcT,
                                            int P, int C, int normBlocks) {
  __shared__ float tile[32][33];
  if ((int)blockIdx.x < normBlocks) {
    int r = (blockIdx.x * 256 + threadIdx.x) >> 6;
    const int lane = threadIdx.x & 63;
    const float4* xr;
    uchar_t* o8;
    if (r < rowsH) {
      xr = h + (size_t)r * 192;          // 768 floats = 192 float4
      o8 = h8;
    } else {
      r -= rowsH;
      if (r >= rowsP) return;
      xr = p + (size_t)r * 192;
      o8 = p8;
    }
    float4 v0 = xr[lane];
    float4 v1 = xr[lane + 64];
    float4 v2 = xr[lane + 128];
    float ss = v0.x * v0.x + v0.y * v0.y + v0.z * v0.z + v0.w * v0.w
             + v1.x * v1.x + v1.y * v1.y + v1.z * v1.z + v1.w * v1.w
             + v2.x * v2.x + v2.y * v2.y + v2.z * v2.z + v2.w * v2.w;
#pragma unroll
    for (int off = 32; off > 0; off >>= 1) ss += __shfl_xor(ss, off, 64);
    const float sc = 4.0f / fmaxf(sqrtf(ss), 1e-12f);
    // lane L holds elements 4L..4L+3 of each 256-element group
    const int rb = r >> 4, rl = r & 15;
    const int key = (rl >> 1) & 7;
    const int cc = (lane & 15) >> 1;                  // logical 8-B chunk
    const int cphys = ((cc ^ key) << 3) + ((lane & 1) << 2);
    const int ktb = lane >> 4;                        // tile within group
    uchar_t* rowbase = o8 + (size_t)rb * 12 * 1024 + rl * 64 + cphys;
    *(uint_t*)(rowbase + (size_t)(ktb) * 1024)     = pack_fp8x4(v0, sc);
    *(uint_t*)(rowbase + (size_t)(4 + ktb) * 1024) = pack_fp8x4(v1, sc);
    *(uint_t*)(rowbase + (size_t)(8 + ktb) * 1024) = pack_fp8x4(v2, sc);
  } else {
    const int b = blockIdx.x - normBlocks;
    const int nkb = P / 32;                   // k-tiles per pcT row-block (=64)
    const int bk = b % nkb, bc = b / nkb;
    const int k0 = bk * 32, c0 = bc * 32;
    const int tx = threadIdx.x & 31, ty = threadIdx.x >> 5;   // ty 0..7
#pragma unroll
    for (int rr = 0; rr < 4; ++rr) {
      const int c = c0 + tx;
      tile[ty + rr * 8][tx] = (c < C) ? pc[(size_t)(k0 + ty + rr * 8) * C + c] : 0.f;
    }
    __syncthreads();
    const int c2 = tx >> 3, off = tx & 7;
#pragma unroll
    for (int rr = 0; rr < 4; ++rr) {
      const int row = c0 + ty + rr * 8;       // pcT row (class dim)
      const int rb = row >> 4, rl = row & 15;
      const int key4 = (rl >> 1) & 3;
      size_t us = (((size_t)rb * nkb + bk) * 16 + rl) * 32 + ((c2 ^ key4) << 3) + off;
      pcT[us] = f32_to_bf16_bits(tile[tx][ty + rr * 8]);
    }
  }
}

// ---------------- GEMM1: 128x128 fp8 MFMA, BK=128 (6 iters), tiled, XCD-swizzled ----------------
// act[N,P](bf16 tiled) = epilogue( h8 @ p8^T ), fp8 e4m3 scale x4 (acc = 16*dot).
// Known-good R0 structure + rsqrt epilogue (R4/R7, verified passing).
__launch_bounds__(256)
__global__ void gemm1_fp8(const uchar_t* __restrict__ A, const uchar_t* __restrict__ B,
                          ushort_t* __restrict__ act, const float* __restrict__ tptr,
                          int nKt, int actKT, int gx, int gxlog2) {
  __shared__ __align__(16) uchar_t As[16384];   // 8 row-tiles x 2 k-tiles x 1 KB
  __shared__ __align__(16) uchar_t Bs[16384];
  const int tid = threadIdx.x, lane = tid & 63, wave = tid >> 6;
  const int wm = wave >> 1, wn = wave & 1;      // 2x2 wave grid, 64x64 each
  const int lid = blockIdx.x, xcd = lid & 7, q = lid >> 3;
  const int t = q & (gx - 1);
  const int s = ((q >> gxlog2) << 3) | xcd;

  f32x4 acc[4][4];
#pragma unroll
  for (int i = 0; i < 4; ++i)
#pragma unroll
    for (int j = 0; j < 4; ++j) acc[i][j] = (f32x4){0.f, 0.f, 0.f, 0.f};

  // staging: wave covers row-tiles {2w,2w+1} x k-tiles {2kt,2kt+1}; 1 KB per call
  const uchar_t* aW = A + ((size_t)(s * 8 + 2 * wave) * nKt) * 1024 + lane * 16;
  const uchar_t* bW = B + ((size_t)(t * 8 + 2 * wave) * nKt) * 1024 + lane * 16;
  const size_t rstride = (size_t)nKt * 1024;
  uchar_t* lA = &As[wave * 4096];
  uchar_t* lB = &Bs[wave * 4096];

  const int fr = lane & 15, g = lane >> 4;
  const int key = (fr >> 1) & 7;
  const int rowoff = fr * 64;
  const int cp0 = ((g ^ key) << 3);             // ksub=0: logical chunk g
  const int cp1 = (((g | 4) ^ key) << 3);       // ksub=1: logical chunk g+4

  const int nIter = nKt >> 1;                   // 6
  for (int kt = 0; kt < nIter; ++kt) {
    const size_t koff = (size_t)(2 * kt) * 1024;
    __syncthreads();  // previous tile's LDS reads done
    gld_lds16(aW + koff, lA);
    gld_lds16(aW + koff + 1024, lA + 1024);
    gld_lds16(aW + rstride + koff, lA + 2048);
    gld_lds16(aW + rstride + koff + 1024, lA + 3072);
    gld_lds16(bW + koff, lB);
    gld_lds16(bW + koff + 1024, lB + 1024);
    gld_lds16(bW + rstride + koff, lB + 2048);
    gld_lds16(bW + rstride + koff + 1024, lB + 3072);
    __syncthreads();  // staging complete

#pragma unroll
    for (int kk = 0; kk < 2; ++kk) {
#pragma unroll
      for (int ksub = 0; ksub < 2; ++ksub) {
        const int cp = ksub ? cp1 : cp0;
        long a[4], b[4];
#pragma unroll
        for (int i = 0; i < 4; ++i)
          a[i] = *(const long*)&As[((wm * 4 + i) * 2 + kk) * 1024 + rowoff + cp];
#pragma unroll
        for (int j = 0; j < 4; ++j)
          b[j] = *(const long*)&Bs[((wn * 4 + j) * 2 + kk) * 1024 + rowoff + cp];
#pragma unroll
        for (int i = 0; i < 4; ++i)
#pragma unroll
          for (int j = 0; j < 4; ++j)
            acc[i][j] = __builtin_amdgcn_mfma_f32_16x16x32_fp8_fp8(a[i], b[j], acc[i][j], 0, 0, 0);
      }
    }
  }

  float tmp = *tptr;
  const float tau = log1pf(expf(tmp));
  // C/D layout: col = lane&15, row = (lane>>4)*4 + reg   [measured m89/m91]
  const int crow = g * 4, ccol = fr;
  const int rowB = s * 128 + wm * 64, colB = t * 128 + wn * 64;
#pragma unroll
  for (int i = 0; i < 4; ++i)
#pragma unroll
    for (int j = 0; j < 4; ++j) {
      const int col = colB + j * 16 + ccol;
      const size_t ktile = col >> 5;
      const int c2 = (col >> 3) & 3, co = col & 7;
#pragma unroll
      for (int rr = 0; rr < 4; ++rr) {
        const int row = rowB + i * 16 + crow + rr;
        const int rb = row >> 4, rl = row & 15;
        const int key4 = (rl >> 1) & 3;
        float d2 = fmaxf(2.0f - acc[i][j][rr] * 0.125f, 0.0f);   // acc = 16*dot
        // sqrt via v_rsq: d2*rsqrt(d2); d2=0 -> 0 (clamped arg avoids 0*inf)
        float d = d2 * rsqrtf(fmaxf(d2, 1e-20f));
        float a = __expf(-tau * d);
        act[(((size_t)rb * actKT + ktile) * 16 + rl) * 32 + ((c2 ^ key4) << 3) + co] =
            f32_to_bf16_bits(a);
      }
    }
}

// ---------------- GEMM2: 128x256 bf16, BK=32, TRIPLE-buffered, 2 blocks/CU (TLP) ----------------
// out[N,C](f32) = act @ pcT^T.  BM=128, BN=256, BK=32 (nKt=64), 8 waves (2M x 4N),
// per-wave 64x64 output (acc 4x4 f32x4 = 64 AGPR -> fits 4 waves/SIMD = 2 blocks/CU).
// LDS = 3 bufs x (A 8K + B 16K) = 72 KB -> 2 blocks/CU resident: the convoy stalls
// of one block hide under the other block's MFMA (cross-block TLP, the mechanism
// that works in gemm1's multi-block structure; intra-wave pipelining failed R3/R4).
// Per K-tile (1 phase): {8 ds_read_b128 | stage tile kt+2 -> buf((kt+2)%3) (3 gld/wave)
//   | BARRIER | lgkm0 | 16 MFMA | vmcnt gate | BARRIER}.
// Region proof: stage(kt+2) targets the buffer holding tile kt-1, whose readers all
// drained (each wave's lgkm0) before the end-of-phase-(kt-1) barrier -- one barrier
// before the stage issues.  Gate after MFMA: outstanding stages newest-first =
// [kt+2 x3][kt+1 x3]; vmcnt(3) leaves only kt+2 -> tile kt+1 fully landed before
// the next phase's reads.  Tail: kt+2>=nKt -> VM0 (drains kt+1); last iter: none.
// Prologue: stage t0 (3 calls, oldest) + t1 (3); VM3 drains t0.
#define BARRIER() do { asm volatile("" ::: "memory"); __builtin_amdgcn_s_barrier(); \
                       asm volatile("" ::: "memory"); } while (0)
#define LGKM0()   asm volatile("s_waitcnt lgkmcnt(0)" ::: "memory")
#define VM3()     asm volatile("s_waitcnt vmcnt(3)" ::: "memory")
#define VM0()     asm volatile("s_waitcnt vmcnt(0)" ::: "memory")
#define PRIO1()   __builtin_amdgcn_s_setprio(1)
#define PRIO0()   __builtin_amdgcn_s_setprio(0)
#define MM(a, b, c) __builtin_amdgcn_mfma_f32_16x16x32_bf16(a, b, c, 0, 0, 0)

__launch_bounds__(512, 4)
__global__ void gemm2_bf16_t3(const ushort_t* __restrict__ A,
                              const ushort_t* __restrict__ B,
                              float* __restrict__ out, int ldc, int ncols,
                              int nKt) {
  __shared__ __align__(16) uchar_t sm[73728];   // 3 x (A 8K + B 16K)
  const int tid = threadIdx.x, lane = tid & 63, wave = tid >> 6;   // 8 waves
  const int wm = wave >> 2, wn = wave & 3;                         // 2M x 4N, 64x64 each
  const int lid = blockIdx.x, xcd = lid & 7, q = lid >> 3;
  const int tb = q & 3, sb = ((q >> 2) << 3) | xcd;   // col-tile 0..3, row-tile 0..127

  f32x4 acc[4][4];
#pragma unroll
  for (int i = 0; i < 4; ++i)
#pragma unroll
    for (int j = 0; j < 4; ++j) acc[i][j] = (f32x4){0.f, 0.f, 0.f, 0.f};

  // global bases: A row-block stride = nKt KB; B col-block stride = nKt KB
  const uchar_t* Apl = (const uchar_t*)A + (((size_t)(sb * 8) * nKt) << 10) + lane * 16;
  const uchar_t* Bpl = (const uchar_t*)B + (((size_t)(tb * 16) * nKt) << 10) + lane * 16;

  // per-lane fragment offset within a unit tile (16-B chunk XOR key)
  const int fr = lane & 15, g = lane >> 4;
  const int rdoff = fr * 64 + ((g ^ ((fr >> 1) & 3)) << 4);
  const uchar_t* smA = sm + (wm << 12) + rdoff;          // + buf offset at use
  const uchar_t* smB = sm + 8192 + (wn << 12) + rdoff;

  // stage roles (3 calls/wave/K-tile): wave w stages A tile {w}, B tiles {w, w+8}
#define T3_STA(r_, T_, bo_) gld_lds16(Apl + ((size_t)((r_) * nKt + (T_)) << 10), \
                                      sm + (bo_) + ((r_) << 10))
#define T3_STB(c_, T_, bo_) gld_lds16(Bpl + ((size_t)((c_) * nKt + (T_)) << 10), \
                                      sm + (bo_) + 8192 + ((c_) << 10))
#define T3_DSA(bo_, i_) (*(const bf16x8*)(smA + (bo_) + ((i_) << 10)))
#define T3_DSB(bo_, j_) (*(const bf16x8*)(smB + (bo_) + ((j_) << 10)))

  // prologue: tile 0 (oldest 3), tile 1 (3); VM3 drains tile 0
  T3_STA(wave, 0, 0); T3_STB(wave, 0, 0); T3_STB(wave + 8, 0, 0);
  T3_STA(wave, 1, 24576); T3_STB(wave, 1, 24576); T3_STB(wave + 8, 1, 24576);
  VM3(); BARRIER();

  int boC = 0, boN = 24576, boNN = 49152;
  for (int kt = 0; kt < nKt; ++kt) {
    bf16x8 a0 = T3_DSA(boC, 0), a1 = T3_DSA(boC, 1), a2 = T3_DSA(boC, 2), a3 = T3_DSA(boC, 3);
    bf16x8 b0 = T3_DSB(boC, 0), b1 = T3_DSB(boC, 1), b2 = T3_DSB(boC, 2), b3 = T3_DSB(boC, 3);
    if (kt + 2 < nKt) {
      T3_STA(wave, kt + 2, boNN); T3_STB(wave, kt + 2, boNN); T3_STB(wave + 8, kt + 2, boNN);
    }
    BARRIER(); LGKM0();
    PRIO1();
    acc[0][0] = MM(a0, b0, acc[0][0]); acc[0][1] = MM(a0, b1, acc[0][1]);
    acc[0][2] = MM(a0, b2, acc[0][2]); acc[0][3] = MM(a0, b3, acc[0][3]);
    acc[1][0] = MM(a1, b0, acc[1][0]); acc[1][1] = MM(a1, b1, acc[1][1]);
    acc[1][2] = MM(a1, b2, acc[1][2]); acc[1][3] = MM(a1, b3, acc[1][3]);
    acc[2][0] = MM(a2, b0, acc[2][0]); acc[2][1] = MM(a2, b1, acc[2][1]);
    acc[2][2] = MM(a2, b2, acc[2][2]); acc[2][3] = MM(a2, b3, acc[2][3]);
    acc[3][0] = MM(a3, b0, acc[3][0]); acc[3][1] = MM(a3, b1, acc[3][1]);
    acc[3][2] = MM(a3, b2, acc[3][2]); acc[3][3] = MM(a3, b3, acc[3][3]);
    PRIO0();
    if (kt + 2 < nKt) { VM3(); } else if (kt + 1 < nKt) { VM0(); }
    BARRIER();
    int tswap = boC; boC = boN; boN = boNN; boNN = tswap;
  }

  // epilogue: C/D layout col = lane&15, row = (lane>>4)*4 + reg
  const int crow = g * 4;
  const int rowB = sb * 128 + wm * 64, colB = tb * 256 + wn * 64;
#pragma unroll
  for (int i = 0; i < 4; ++i)
#pragma unroll
    for (int j = 0; j < 4; ++j) {
      const int col = colB + j * 16 + fr;
      if (col < ncols) {
#pragma unroll
        for (int rr = 0; rr < 4; ++rr)
          out[(size_t)(rowB + i * 16 + crow + rr) * ldc + col] = acc[i][j][rr];
      }
    }
}

extern "C" void kernel_launch(void* const* d_in, const int* in_sizes, int n_in,
                              void* d_out, int out_size, void* d_ws, size_t ws_size,
                              hipStream_t stream) {
  const float* h    = (const float*)d_in[0];
  const float* prot = (const float*)d_in[1];
  const float* pc   = (const float*)d_in[2];
  const float* temp = (const float*)d_in[3];
  float* out = (float*)d_out;

  const int D = 768;
  const int N = in_sizes[0] / D;          // 16384
  const int P = in_sizes[1] / D;          // 2048
  const int C = in_sizes[2] / P;          // 1000
  const int CP = (C + 127) & ~127;        // 1024 (padded)

  // workspace layout (16B aligned), all tiled
  char* ws = (char*)d_ws;
  size_t off = 0;
  uchar_t* h8   = (uchar_t*)(ws + off); off += (size_t)N * D;         // 12.6 MB fp8
  uchar_t* p8   = (uchar_t*)(ws + off); off += (size_t)P * D;         //  1.6 MB fp8
  ushort_t* pcT = (ushort_t*)(ws + off); off += (size_t)CP * P * 2;   //  4.2 MB bf16
  ushort_t* act = (ushort_t*)(ws + off); off += (size_t)N * P * 2;    // 67.1 MB bf16
  (void)ws_size;  // total ~85.5 MB

  // single prep dispatch: normalize (fp8 x4, tiled) + transpose (bf16, tiled)
  const int normBlocks = (N + P) / 4;                 // 4608
  const int transBlocks = (P / 32) * (CP / 32);       // 2048
  prep<<<normBlocks + transBlocks, 256, 0, stream>>>(
      (const float4*)h, h8, N, (const float4*)prot, p8, P,
      pc, pcT, P, C, normBlocks);

  // GEMM1: act[N,P](bf16 tiled) = epilogue(h8 @ p8^T), fp8, BK=128 (known-good 128^2)
  {
    const int GX = P / 128, GY = N / 128;   // 16, 128
    gemm1_fp8<<<GX * GY, 256, 0, stream>>>(h8, p8, act, temp, D / 64, P / 32, GX, 4);
  }
  // GEMM2: out[N,C](f32) = act @ pcT^T, bf16, 128x256 BK=32 triple-buffer, 2 blocks/CU
  {
    const int GX = CP / 256, GY = N / 128;  // 4, 128 -> 512 blocks = 2/CU
    gemm2_bf16_t3<<<GX * GY, 512, 0, stream>>>(act, pcT, out, C, C, P / 32);
  }
}

// Round 10
// 214.204 us; speedup vs baseline: 1.2282x; 1.0129x over previous
//
#include <hip/hip_runtime.h>
#include <hip/hip_bf16.h>
#include <math.h>

typedef unsigned short ushort_t;
typedef unsigned char uchar_t;
typedef unsigned int uint_t;
typedef __attribute__((ext_vector_type(8))) short bf16x8;   // 8 bf16 = 4 VGPRs
typedef __attribute__((ext_vector_type(4))) float f32x4;
typedef __attribute__((ext_vector_type(2))) long longx2;    // 16 B = {ksub0, ksub1} fp8 frags

#define AS1 __attribute__((address_space(1)))
#define AS3 __attribute__((address_space(3)))

__device__ __forceinline__ void gld_lds16(const void* g, void* l) {
  // async global->LDS, 16B per lane; LDS dest = wave-uniform base + lane*16
  __builtin_amdgcn_global_load_lds((const AS1 void*)g, (AS3 void*)l, 16, 0, 0);
}

__device__ __forceinline__ ushort_t f32_to_bf16_bits(float v) {
  __hip_bfloat16 b = __float2bfloat16(v);
  return *(ushort_t*)&b;
}

__device__ __forceinline__ uint_t pack_fp8x4(float4 v, float sc) {
  int r = __builtin_amdgcn_cvt_pk_fp8_f32(v.x * sc, v.y * sc, 0, false);
  r = __builtin_amdgcn_cvt_pk_fp8_f32(v.z * sc, v.w * sc, r, true);
  return (uint_t)r;
}

// ================= tiled operand layout =================
// Unit tile = 16 rows x 64 B, stored contiguously (1024 B). Tile index =
// rowblock * nKtiles + kt. Within a tile row rl, the 64 B is split into 16-B
// units XOR-permuted by a per-row key so MFMA fragment ds_read_b128 are
// conflict-free:
//   bf16: unit u = k[16u..16u+16);      phys = u ^ ((rl>>1)&3)
//   fp8 : unit u = {ksub0 k[8u..8u+8) | ksub1 k[32+8u..+8)};  phys = u ^ ((rl>>1)&3)
// (fp8 pairs the two ksub fragments adjacently so one b128 feeds both MFMAs —
//  R2-verified end-to-end.)  global_load_lds copies tiles verbatim.

// ---------------- single prep kernel ----------------
__global__ __launch_bounds__(256) void prep(const float4* __restrict__ h,
                                            uchar_t* __restrict__ h8, int rowsH,
                                            const float4* __restrict__ p,
                                            uchar_t* __restrict__ p8, int rowsP,
                                            const float* __restrict__ pc,
                                            ushort_t* __restrict__ pcT,
                                            int P, int C, int normBlocks) {
  __shared__ float tile[32][33];
  if ((int)blockIdx.x < normBlocks) {
    int r = (blockIdx.x * 256 + threadIdx.x) >> 6;
    const int lane = threadIdx.x & 63;
    const float4* xr;
    uchar_t* o8;
    if (r < rowsH) {
      xr = h + (size_t)r * 192;          // 768 floats = 192 float4
      o8 = h8;
    } else {
      r -= rowsH;
      if (r >= rowsP) return;
      xr = p + (size_t)r * 192;
      o8 = p8;
    }
    float4 v0 = xr[lane];
    float4 v1 = xr[lane + 64];
    float4 v2 = xr[lane + 128];
    float ss = v0.x * v0.x + v0.y * v0.y + v0.z * v0.z + v0.w * v0.w
             + v1.x * v1.x + v1.y * v1.y + v1.z * v1.z + v1.w * v1.w
             + v2.x * v2.x + v2.y * v2.y + v2.z * v2.z + v2.w * v2.w;
#pragma unroll
    for (int off = 32; off > 0; off >>= 1) ss += __shfl_xor(ss, off, 64);
    const float sc = 4.0f / fmaxf(sqrtf(ss), 1e-12f);
    // lane L holds k-local = 4*(L&15)+{0..3} of tile ktb = L>>4 in each 256-group.
    // fp8 paired-unit layout (R2-verified): u=(L&7)>>1, ksub=(L&15)>>3, inner=4*(L&1)
    const int rb = r >> 4, rl = r & 15;
    const int key4 = (rl >> 1) & 3;
    const int u = (lane & 7) >> 1;
    const int ksub = (lane & 15) >> 3;
    const int cphys = ((u ^ key4) << 4) + (ksub << 3) + ((lane & 1) << 2);
    const int ktb = lane >> 4;                        // tile within group
    uchar_t* rowbase = o8 + (size_t)rb * 12 * 1024 + rl * 64 + cphys;
    *(uint_t*)(rowbase + (size_t)(ktb) * 1024)     = pack_fp8x4(v0, sc);
    *(uint_t*)(rowbase + (size_t)(4 + ktb) * 1024) = pack_fp8x4(v1, sc);
    *(uint_t*)(rowbase + (size_t)(8 + ktb) * 1024) = pack_fp8x4(v2, sc);
  } else {
    const int b = blockIdx.x - normBlocks;
    const int nkb = P / 32;                   // k-tiles per pcT row-block (=64)
    const int bk = b % nkb, bc = b / nkb;
    const int k0 = bk * 32, c0 = bc * 32;
    const int tx = threadIdx.x & 31, ty = threadIdx.x >> 5;   // ty 0..7
#pragma unroll
    for (int rr = 0; rr < 4; ++rr) {
      const int c = c0 + tx;
      tile[ty + rr * 8][tx] = (c < C) ? pc[(size_t)(k0 + ty + rr * 8) * C + c] : 0.f;
    }
    __syncthreads();
    const int c2 = tx >> 3, off = tx & 7;
#pragma unroll
    for (int rr = 0; rr < 4; ++rr) {
      const int row = c0 + ty + rr * 8;       // pcT row (class dim)
      const int rb = row >> 4, rl = row & 15;
      const int key4 = (rl >> 1) & 3;
      size_t us = (((size_t)rb * nkb + bk) * 16 + rl) * 32 + ((c2 ^ key4) << 3) + off;
      pcT[us] = f32_to_bf16_bits(tile[tx][ty + rr * 8]);
    }
  }
}

// ======== shared schedule primitives (t3 skeleton, R9-verified) ========
#define BARRIER() do { asm volatile("" ::: "memory"); __builtin_amdgcn_s_barrier(); \
                       asm volatile("" ::: "memory"); } while (0)
#define LGKM0()   asm volatile("s_waitcnt lgkmcnt(0)" ::: "memory")
#define VM3()     asm volatile("s_waitcnt vmcnt(3)" ::: "memory")
#define VM0()     asm volatile("s_waitcnt vmcnt(0)" ::: "memory")
#define PRIO1()   __builtin_amdgcn_s_setprio(1)
#define PRIO0()   __builtin_amdgcn_s_setprio(0)
#define MM(a, b, c)  __builtin_amdgcn_mfma_f32_16x16x32_bf16(a, b, c, 0, 0, 0)
#define MM8(a, b, c) __builtin_amdgcn_mfma_f32_16x16x32_fp8_fp8(a, b, c, 0, 0, 0)

// ---------------- GEMM1: 128x256 fp8, BK=64, TRIPLE-buffered, 2 blocks/CU (t3) ----------------
// act[N,P](bf16 tiled) = epilogue( h8 @ p8^T ).  BM=128, BN=256, BK=64 (nKt=12),
// 8 waves (2M x 4N), 64x64 output/wave (acc 4x4 f32x4 = 64 VGPR).
// LDS = 3 bufs x (A 8K + B 16K) = 72 KB -> 2 blocks/CU (the R9-verified TLP mechanism).
// Per K-tile (1 phase): {8 ds_read_b128 (longx2: both fp8 ksubs) | stage tile kt+2 ->
//   buf((kt+2)%3) (3 gld/wave: A{w}, B{w}, B{w+8}) | BARRIER | lgkm0 | 32 MFMA |
//   vmcnt gate | BARRIER}.  Identical stage counts to gemm2_t3 -> identical region &
//   vmcnt proof: stage(kt+2) overwrites tile kt-1's buffer (readers drained one
//   barrier earlier); VM3 after MFMA leaves only kt+2's 3 calls -> kt+1 landed.
__launch_bounds__(512, 4)
__global__ void gemm1_fp8_t3(const uchar_t* __restrict__ A, const uchar_t* __restrict__ B,
                             ushort_t* __restrict__ act, const float* __restrict__ tptr,
                             int nKt, int actKT, int gx, int gxlog2) {
  __shared__ __align__(16) uchar_t sm1[73728];   // 3 x (A 8K + B 16K)
  const int tid = threadIdx.x, lane = tid & 63, wave = tid >> 6;   // 8 waves
  const int wm = wave >> 2, wn = wave & 3;                         // 2M x 4N, 64x64 each
  const int lid = blockIdx.x, xcd = lid & 7, q = lid >> 3;
  const int tb = q & (gx - 1), sb = ((q >> gxlog2) << 3) | xcd;    // 8 x 128 grid

  f32x4 acc[4][4];
#pragma unroll
  for (int i = 0; i < 4; ++i)
#pragma unroll
    for (int j = 0; j < 4; ++j) acc[i][j] = (f32x4){0.f, 0.f, 0.f, 0.f};

  const uchar_t* Apl = A + (((size_t)(sb * 8) * nKt) << 10) + lane * 16;
  const uchar_t* Bpl = B + (((size_t)(tb * 16) * nKt) << 10) + lane * 16;

  // per-lane fragment offset within a unit tile (16-B unit XOR key)
  const int fr = lane & 15, g = lane >> 4;
  const int rdoff = fr * 64 + ((g ^ ((fr >> 1) & 3)) << 4);
  const uchar_t* smA = sm1 + (wm << 12) + rdoff;          // + buf offset at use
  const uchar_t* smB = sm1 + 8192 + (wn << 12) + rdoff;

  // stage roles (3 calls/wave/K-tile): wave w stages A tile {w}, B tiles {w, w+8}
#define G1_STA(r_, T_, bo_) gld_lds16(Apl + ((size_t)((r_) * nKt + (T_)) << 10), \
                                      sm1 + (bo_) + ((r_) << 10))
#define G1_STB(c_, T_, bo_) gld_lds16(Bpl + ((size_t)((c_) * nKt + (T_)) << 10), \
                                      sm1 + (bo_) + 8192 + ((c_) << 10))
#define G1_DSA(bo_, i_) (*(const longx2*)(smA + (bo_) + ((i_) << 10)))
#define G1_DSB(bo_, j_) (*(const longx2*)(smB + (bo_) + ((j_) << 10)))

  // prologue: tile 0 (oldest 3), tile 1 (3); VM3 drains tile 0
  G1_STA(wave, 0, 0); G1_STB(wave, 0, 0); G1_STB(wave + 8, 0, 0);
  G1_STA(wave, 1, 24576); G1_STB(wave, 1, 24576); G1_STB(wave + 8, 1, 24576);
  VM3(); BARRIER();

  int boC = 0, boN = 24576, boNN = 49152;
  for (int kt = 0; kt < nKt; ++kt) {
    longx2 a0 = G1_DSA(boC, 0), a1 = G1_DSA(boC, 1), a2 = G1_DSA(boC, 2), a3 = G1_DSA(boC, 3);
    longx2 b0 = G1_DSB(boC, 0), b1 = G1_DSB(boC, 1), b2 = G1_DSB(boC, 2), b3 = G1_DSB(boC, 3);
    if (kt + 2 < nKt) {
      G1_STA(wave, kt + 2, boNN); G1_STB(wave, kt + 2, boNN); G1_STB(wave + 8, kt + 2, boNN);
    }
    BARRIER(); LGKM0();
    PRIO1();
    // ksub0 (K 0..31)
    acc[0][0] = MM8(a0[0], b0[0], acc[0][0]); acc[0][1] = MM8(a0[0], b1[0], acc[0][1]);
    acc[0][2] = MM8(a0[0], b2[0], acc[0][2]); acc[0][3] = MM8(a0[0], b3[0], acc[0][3]);
    acc[1][0] = MM8(a1[0], b0[0], acc[1][0]); acc[1][1] = MM8(a1[0], b1[0], acc[1][1]);
    acc[1][2] = MM8(a1[0], b2[0], acc[1][2]); acc[1][3] = MM8(a1[0], b3[0], acc[1][3]);
    acc[2][0] = MM8(a2[0], b0[0], acc[2][0]); acc[2][1] = MM8(a2[0], b1[0], acc[2][1]);
    acc[2][2] = MM8(a2[0], b2[0], acc[2][2]); acc[2][3] = MM8(a2[0], b3[0], acc[2][3]);
    acc[3][0] = MM8(a3[0], b0[0], acc[3][0]); acc[3][1] = MM8(a3[0], b1[0], acc[3][1]);
    acc[3][2] = MM8(a3[0], b2[0], acc[3][2]); acc[3][3] = MM8(a3[0], b3[0], acc[3][3]);
    // ksub1 (K 32..63) — same acc re-touched at distance 16
    acc[0][0] = MM8(a0[1], b0[1], acc[0][0]); acc[0][1] = MM8(a0[1], b1[1], acc[0][1]);
    acc[0][2] = MM8(a0[1], b2[1], acc[0][2]); acc[0][3] = MM8(a0[1], b3[1], acc[0][3]);
    acc[1][0] = MM8(a1[1], b0[1], acc[1][0]); acc[1][1] = MM8(a1[1], b1[1], acc[1][1]);
    acc[1][2] = MM8(a1[1], b2[1], acc[1][2]); acc[1][3] = MM8(a1[1], b3[1], acc[1][3]);
    acc[2][0] = MM8(a2[1], b0[1], acc[2][0]); acc[2][1] = MM8(a2[1], b1[1], acc[2][1]);
    acc[2][2] = MM8(a2[1], b2[1], acc[2][2]); acc[2][3] = MM8(a2[1], b3[1], acc[2][3]);
    acc[3][0] = MM8(a3[1], b0[1], acc[3][0]); acc[3][1] = MM8(a3[1], b1[1], acc[3][1]);
    acc[3][2] = MM8(a3[1], b2[1], acc[3][2]); acc[3][3] = MM8(a3[1], b3[1], acc[3][3]);
    PRIO0();
    if (kt + 2 < nKt) { VM3(); } else if (kt + 1 < nKt) { VM0(); }
    BARRIER();
    int tswap = boC; boC = boN; boN = boNN; boNN = tswap;
  }

  float tmp = *tptr;
  const float tau = log1pf(expf(tmp));
  // C/D layout: col = lane&15, row = (lane>>4)*4 + reg   [measured m89/m91]
  const int crow = g * 4;
  const int rowB = sb * 128 + wm * 64, colB = tb * 256 + wn * 64;
#pragma unroll
  for (int i = 0; i < 4; ++i)
#pragma unroll
    for (int j = 0; j < 4; ++j) {
      const int col = colB + j * 16 + fr;
      const size_t ktile = col >> 5;
      const int c2 = (col >> 3) & 3, co = col & 7;
#pragma unroll
      for (int rr = 0; rr < 4; ++rr) {
        const int row = rowB + i * 16 + crow + rr;
        const int rb = row >> 4, rl = row & 15;
        const int key4 = (rl >> 1) & 3;
        float d2 = fmaxf(2.0f - acc[i][j][rr] * 0.125f, 0.0f);   // acc = 16*dot
        float d = d2 * rsqrtf(fmaxf(d2, 1e-20f));
        float a = __expf(-tau * d);
        act[(((size_t)rb * actKT + ktile) * 16 + rl) * 32 + ((c2 ^ key4) << 3) + co] =
            f32_to_bf16_bits(a);
      }
    }
}

// ---------------- GEMM2: 128x256 bf16, BK=32, TRIPLE-buffered, 2 blocks/CU (TLP) ----------------
// R9-verified: 62 us, MfmaUtil 45%, Occupancy 33%.  out[N,C](f32) = act @ pcT^T.
__launch_bounds__(512, 4)
__global__ void gemm2_bf16_t3(const ushort_t* __restrict__ A,
                              const ushort_t* __restrict__ B,
                              float* __restrict__ out, int ldc, int ncols,
                              int nKt) {
  __shared__ __align__(16) uchar_t sm[73728];   // 3 x (A 8K + B 16K)
  const int tid = threadIdx.x, lane = tid & 63, wave = tid >> 6;   // 8 waves
  const int wm = wave >> 2, wn = wave & 3;                         // 2M x 4N, 64x64 each
  const int lid = blockIdx.x, xcd = lid & 7, q = lid >> 3;
  const int tb = q & 3, sb = ((q >> 2) << 3) | xcd;   // col-tile 0..3, row-tile 0..127

  f32x4 acc[4][4];
#pragma unroll
  for (int i = 0; i < 4; ++i)
#pragma unroll
    for (int j = 0; j < 4; ++j) acc[i][j] = (f32x4){0.f, 0.f, 0.f, 0.f};

  const uchar_t* Apl = (const uchar_t*)A + (((size_t)(sb * 8) * nKt) << 10) + lane * 16;
  const uchar_t* Bpl = (const uchar_t*)B + (((size_t)(tb * 16) * nKt) << 10) + lane * 16;

  const int fr = lane & 15, g = lane >> 4;
  const int rdoff = fr * 64 + ((g ^ ((fr >> 1) & 3)) << 4);
  const uchar_t* smA = sm + (wm << 12) + rdoff;
  const uchar_t* smB = sm + 8192 + (wn << 12) + rdoff;

#define T3_STA(r_, T_, bo_) gld_lds16(Apl + ((size_t)((r_) * nKt + (T_)) << 10), \
                                      sm + (bo_) + ((r_) << 10))
#define T3_STB(c_, T_, bo_) gld_lds16(Bpl + ((size_t)((c_) * nKt + (T_)) << 10), \
                                      sm + (bo_) + 8192 + ((c_) << 10))
#define T3_DSA(bo_, i_) (*(const bf16x8*)(smA + (bo_) + ((i_) << 10)))
#define T3_DSB(bo_, j_) (*(const bf16x8*)(smB + (bo_) + ((j_) << 10)))

  T3_STA(wave, 0, 0); T3_STB(wave, 0, 0); T3_STB(wave + 8, 0, 0);
  T3_STA(wave, 1, 24576); T3_STB(wave, 1, 24576); T3_STB(wave + 8, 1, 24576);
  VM3(); BARRIER();

  int boC = 0, boN = 24576, boNN = 49152;
  for (int kt = 0; kt < nKt; ++kt) {
    bf16x8 a0 = T3_DSA(boC, 0), a1 = T3_DSA(boC, 1), a2 = T3_DSA(boC, 2), a3 = T3_DSA(boC, 3);
    bf16x8 b0 = T3_DSB(boC, 0), b1 = T3_DSB(boC, 1), b2 = T3_DSB(boC, 2), b3 = T3_DSB(boC, 3);
    if (kt + 2 < nKt) {
      T3_STA(wave, kt + 2, boNN); T3_STB(wave, kt + 2, boNN); T3_STB(wave + 8, kt + 2, boNN);
    }
    BARRIER(); LGKM0();
    PRIO1();
    acc[0][0] = MM(a0, b0, acc[0][0]); acc[0][1] = MM(a0, b1, acc[0][1]);
    acc[0][2] = MM(a0, b2, acc[0][2]); acc[0][3] = MM(a0, b3, acc[0][3]);
    acc[1][0] = MM(a1, b0, acc[1][0]); acc[1][1] = MM(a1, b1, acc[1][1]);
    acc[1][2] = MM(a1, b2, acc[1][2]); acc[1][3] = MM(a1, b3, acc[1][3]);
    acc[2][0] = MM(a2, b0, acc[2][0]); acc[2][1] = MM(a2, b1, acc[2][1]);
    acc[2][2] = MM(a2, b2, acc[2][2]); acc[2][3] = MM(a2, b3, acc[2][3]);
    acc[3][0] = MM(a3, b0, acc[3][0]); acc[3][1] = MM(a3, b1, acc[3][1]);
    acc[3][2] = MM(a3, b2, acc[3][2]); acc[3][3] = MM(a3, b3, acc[3][3]);
    PRIO0();
    if (kt + 2 < nKt) { VM3(); } else if (kt + 1 < nKt) { VM0(); }
    BARRIER();
    int tswap = boC; boC = boN; boN = boNN; boNN = tswap;
  }

  // epilogue: C/D layout col = lane&15, row = (lane>>4)*4 + reg
  const int crow = g * 4;
  const int rowB = sb * 128 + wm * 64, colB = tb * 256 + wn * 64;
#pragma unroll
  for (int i = 0; i < 4; ++i)
#pragma unroll
    for (int j = 0; j < 4; ++j) {
      const int col = colB + j * 16 + fr;
      if (col < ncols) {
#pragma unroll
        for (int rr = 0; rr < 4; ++rr)
          out[(size_t)(rowB + i * 16 + crow + rr) * ldc + col] = acc[i][j][rr];
      }
    }
}

extern "C" void kernel_launch(void* const* d_in, const int* in_sizes, int n_in,
                              void* d_out, int out_size, void* d_ws, size_t ws_size,
                              hipStream_t stream) {
  const float* h    = (const float*)d_in[0];
  const float* prot = (const float*)d_in[1];
  const float* pc   = (const float*)d_in[2];
  const float* temp = (const float*)d_in[3];
  float* out = (float*)d_out;

  const int D = 768;
  const int N = in_sizes[0] / D;          // 16384
  const int P = in_sizes[1] / D;          // 2048
  const int C = in_sizes[2] / P;          // 1000
  const int CP = (C + 127) & ~127;        // 1024 (padded)

  // workspace layout (16B aligned), all tiled
  char* ws = (char*)d_ws;
  size_t off = 0;
  uchar_t* h8   = (uchar_t*)(ws + off); off += (size_t)N * D;         // 12.6 MB fp8
  uchar_t* p8   = (uchar_t*)(ws + off); off += (size_t)P * D;         //  1.6 MB fp8
  ushort_t* pcT = (ushort_t*)(ws + off); off += (size_t)CP * P * 2;   //  4.2 MB bf16
  ushort_t* act = (ushort_t*)(ws + off); off += (size_t)N * P * 2;    // 67.1 MB bf16
  (void)ws_size;  // total ~85.5 MB

  // single prep dispatch: normalize (fp8 x4, paired-unit tiled) + transpose (bf16, tiled)
  const int normBlocks = (N + P) / 4;                 // 4608
  const int transBlocks = (P / 32) * (CP / 32);       // 2048
  prep<<<normBlocks + transBlocks, 256, 0, stream>>>(
      (const float4*)h, h8, N, (const float4*)prot, p8, P,
      pc, pcT, P, C, normBlocks);

  // GEMM1: act[N,P](bf16 tiled) = epilogue(h8 @ p8^T), fp8, 128x256 BK=64 t3, 2 blocks/CU
  {
    const int GX = P / 256, GY = N / 128;   // 8, 128 -> 1024 blocks
    gemm1_fp8_t3<<<GX * GY, 512, 0, stream>>>(h8, p8, act, temp, D / 64, P / 32, GX, 3);
  }
  // GEMM2: out[N,C](f32) = act @ pcT^T, bf16, 128x256 BK=32 triple-buffer, 2 blocks/CU
  {
    const int GX = CP / 256, GY = N / 128;  // 4, 128 -> 512 blocks = 2/CU
    gemm2_bf16_t3<<<GX * GY, 512, 0, stream>>>(act, pcT, out, C, C, P / 32);
  }
}